// Round 8
// baseline (1087.591 us; speedup 1.0000x reference)
//
#include <hip/hip_runtime.h>
#include <hip/hip_bf16.h>
#include <stdint.h>

#define N_NODES 65536
#define N_EDGES (N_NODES * 16)
#define NEG_SLOPE 0.2f

typedef short bf16x8 __attribute__((ext_vector_type(8)));   // 8 bf16 in 4 VGPRs
typedef float f32x4 __attribute__((ext_vector_type(4)));

__device__ __forceinline__ unsigned short f2bf(float f) {
    unsigned u = __float_as_uint(f);
    u += 0x7fffu + ((u >> 16) & 1u);       // RNE
    return (unsigned short)(u >> 16);
}
__device__ __forceinline__ float bf2f(unsigned short h) {
    return __uint_as_float(((unsigned)h) << 16);
}
__device__ __forceinline__ void load_lds16(const void* g, void* l) {
    __builtin_amdgcn_global_load_lds(
        (const __attribute__((address_space(1))) unsigned int*)g,
        (__attribute__((address_space(3))) unsigned int*)l, 16, 0, 0);
}

// ---------------- MFMA GEMM: C[M,Nw] = A[M,Kp] @ Wt^T (+bias,+relu) ----------------
// A: fp32 (A32 path, converted during staging) or bf16 hi/lo pair.
// Wt transposed [n][Kp] bf16 hi/lo, zero-padded.
// Split-bf16: acc += Ahi*Bhi + Alo*Bhi + Ahi*Blo  (fp32 MFMA accumulate).
// Block 256 = 4 waves; tile 128(M) x TN(N), TN in {64,128}; BK=32.
// If asrc != null: also computes per-row attention dots al_s/al_d (atomicAdd).
template<int TN>
__global__ __launch_bounds__(256) void gemm_mfma(
    const float* __restrict__ A32, int KA,
    const unsigned short* __restrict__ Ahi, const unsigned short* __restrict__ Alo,
    int lda, int Kp,
    const unsigned short* __restrict__ Bhi, const unsigned short* __restrict__ Blo,
    const float* __restrict__ bias, int Nbias,
    float* __restrict__ C32,
    unsigned short* __restrict__ Chi, unsigned short* __restrict__ Clo,
    int ldc, int Nw, int relu,
    const float* __restrict__ asrc, const float* __restrict__ adst,
    float* __restrict__ alS, float* __restrict__ alD, int Cal, int HCal)
{
    constexpr int NI = TN / 32;                 // N-frags per wave
    __shared__ unsigned short sAhi[128 * 32], sAlo[128 * 32];
    __shared__ unsigned short sBhi[TN * 32],  sBlo[TN * 32];
    __shared__ float sAl[128][2][4];
    const int tid = threadIdx.x;
    const int wave = tid >> 6, lane = tid & 63;
    const int row0 = blockIdx.y * 128;
    const int col0 = blockIdx.x * TN;
    const int wm = (wave & 1) * 64, wn = (wave >> 1) * (TN / 2);
    const int mlane = lane & 15, q = lane >> 4;

    f32x4 acc[4][NI];
#pragma unroll
    for (int a = 0; a < 4; ++a)
#pragma unroll
        for (int b = 0; b < NI; ++b) acc[a][b] = (f32x4){0.f, 0.f, 0.f, 0.f};

    for (int k0 = 0; k0 < Kp; k0 += 32) {
        __syncthreads();
        if (A32) {
            // fp32 -> bf16 hi/lo conversion staging (layer 1 only)
            const int r = tid >> 1, cbase = (tid & 1) * 16;
            const float* Ap = A32 + (size_t)(row0 + r) * lda;
#pragma unroll
            for (int j = 0; j < 4; ++j) {
                int kc = k0 + cbase + j * 4;
                float4 v = make_float4(0.f, 0.f, 0.f, 0.f);
                if (kc < KA) v = *(const float4*)(Ap + kc);
                ushort4 h, l;
                h.x = f2bf(v.x); l.x = f2bf(v.x - bf2f(h.x));
                h.y = f2bf(v.y); l.y = f2bf(v.y - bf2f(h.y));
                h.z = f2bf(v.z); l.z = f2bf(v.z - bf2f(h.z));
                h.w = f2bf(v.w); l.w = f2bf(v.w - bf2f(h.w));
                *(ushort4*)(sAhi + r * 32 + cbase + j * 4) = h;
                *(ushort4*)(sAlo + r * 32 + cbase + j * 4) = l;
            }
        } else {
            // async global->LDS, 16B/lane; LDS dst = wave-uniform base + lane*16
#pragma unroll
            for (int cc = 0; cc < 2; ++cc) {
                int c = wave * 2 + cc;                 // 8 chunks of 16 rows
                int r = c * 16 + (lane >> 2);
                size_t goff = (size_t)(row0 + r) * lda + k0 + (lane & 3) * 8;
                load_lds16(Ahi + goff, sAhi + c * 512);
                load_lds16(Alo + goff, sAlo + c * 512);
            }
        }
        {
#pragma unroll
            for (int cc = 0; cc < TN / 64; ++cc) {
                int c = wave * (TN / 64) + cc;         // TN/16 chunks of 16 rows
                int r = c * 16 + (lane >> 2);
                size_t goff = (size_t)(col0 + r) * Kp + k0 + (lane & 3) * 8;
                load_lds16(Bhi + goff, sBhi + c * 512);
                load_lds16(Blo + goff, sBlo + c * 512);
            }
        }
        __syncthreads();

        bf16x8 ah[4], al[4], bh[NI], bl[NI];
#pragma unroll
        for (int mi = 0; mi < 4; ++mi) {
            int m = wm + mi * 16 + mlane;
            ah[mi] = *(const bf16x8*)(sAhi + m * 32 + q * 8);
            al[mi] = *(const bf16x8*)(sAlo + m * 32 + q * 8);
        }
#pragma unroll
        for (int ni = 0; ni < NI; ++ni) {
            int n = wn + ni * 16 + mlane;
            bh[ni] = *(const bf16x8*)(sBhi + n * 32 + q * 8);
            bl[ni] = *(const bf16x8*)(sBlo + n * 32 + q * 8);
        }
#pragma unroll
        for (int mi = 0; mi < 4; ++mi)
#pragma unroll
            for (int ni = 0; ni < NI; ++ni) {
                acc[mi][ni] = __builtin_amdgcn_mfma_f32_16x16x32_bf16(ah[mi], bh[ni], acc[mi][ni], 0, 0, 0);
                acc[mi][ni] = __builtin_amdgcn_mfma_f32_16x16x32_bf16(al[mi], bh[ni], acc[mi][ni], 0, 0, 0);
                acc[mi][ni] = __builtin_amdgcn_mfma_f32_16x16x32_bf16(ah[mi], bl[ni], acc[mi][ni], 0, 0, 0);
            }
    }

    // epilogue: C/D frag layout col=lane&15, row=(lane>>4)*4+reg
#pragma unroll
    for (int ni = 0; ni < NI; ++ni) {
        int col = col0 + wn + ni * 16 + mlane;
        if (col >= Nw) continue;
        float bv = (bias && col < Nbias) ? bias[col] : 0.f;
#pragma unroll
        for (int mi = 0; mi < 4; ++mi) {
#pragma unroll
            for (int reg = 0; reg < 4; ++reg) {
                int row = row0 + wm + mi * 16 + q * 4 + reg;
                float v = acc[mi][ni][reg] + bv;
                if (relu) v = fmaxf(v, 0.f);
                size_t off = (size_t)row * ldc + col;
                if (Chi) {
                    unsigned short h = f2bf(v);
                    Chi[off] = h;
                    Clo[off] = f2bf(v - bf2f(h));
                } else {
                    C32[off] = v;
                }
            }
        }
    }

    // fused attention-logit dots: al_s[row,h] += sum_c h[row,c]*a_s[h,c], same for a_d
    if (asrc) {
        float asv[NI], adv[NI];
        bool head0[NI];
#pragma unroll
        for (int ni = 0; ni < NI; ++ni) {
            int col = col0 + wn + ni * 16 + mlane;
            bool valid = col < HCal;
            head0[ni] = col < Cal;
            asv[ni] = valid ? asrc[col] : 0.f;
            adv[ni] = valid ? adst[col] : 0.f;
        }
#pragma unroll
        for (int mi = 0; mi < 4; ++mi) {
#pragma unroll
            for (int reg = 0; reg < 4; ++reg) {
                float s0 = 0.f, s1 = 0.f, d0 = 0.f, d1 = 0.f;
#pragma unroll
                for (int ni = 0; ni < NI; ++ni) {
                    float v = acc[mi][ni][reg];
                    if (head0[ni]) { s0 += v * asv[ni]; d0 += v * adv[ni]; }
                    else           { s1 += v * asv[ni]; d1 += v * adv[ni]; }
                }
#pragma unroll
                for (int off = 1; off < 16; off <<= 1) {
                    s0 += __shfl_xor(s0, off); s1 += __shfl_xor(s1, off);
                    d0 += __shfl_xor(d0, off); d1 += __shfl_xor(d1, off);
                }
                if (mlane == 0) {
                    int rl = wm + mi * 16 + q * 4 + reg;
                    int slot = wave >> 1;
                    sAl[rl][slot][0] = s0; sAl[rl][slot][1] = s1;
                    sAl[rl][slot][2] = d0; sAl[rl][slot][3] = d1;
                }
            }
        }
        __syncthreads();
        if (tid < 128) {
            int row = row0 + tid;
            float v0 = sAl[tid][0][0] + sAl[tid][1][0];
            float v1 = sAl[tid][0][1] + sAl[tid][1][1];
            float v2 = sAl[tid][0][2] + sAl[tid][1][2];
            float v3 = sAl[tid][0][3] + sAl[tid][1][3];
            atomicAdd(&alS[row * 2 + 0], v0);
            atomicAdd(&alS[row * 2 + 1], v1);
            atomicAdd(&alD[row * 2 + 0], v2);
            atomicAdd(&alD[row * 2 + 1], v3);
        }
    }
}

// ---------------- weight transpose + bf16 hi/lo decompose (all 8 in one) ----------
struct WtJob {
    const float* W; unsigned short* Whi; unsigned short* Wlo;
    int K, N, Kp, remap, nb0;
};
struct WtJobs { WtJob j[8]; };

__global__ void wt_decomp_all(WtJobs jobs)
{
    int b = blockIdx.x;
    int idx = 0;
#pragma unroll
    for (int i = 1; i < 8; ++i)
        if (b >= jobs.j[i].nb0) idx = i;
    WtJob jb = jobs.j[idx];
    int n = b - jb.nb0;
    for (int k = threadIdx.x; k < jb.Kp; k += 256) {
        int ks = k, valid = 1;
        if (jb.remap) {
            int bb = k >> 6, r = k & 63;
            if (r < 60) ks = bb * 60 + r; else valid = 0;
        }
        float v = 0.f;
        if (valid && ks < jb.K && n < jb.N) v = jb.W[(size_t)ks * jb.N + n];
        unsigned short h = f2bf(v);
        jb.Whi[(size_t)n * jb.Kp + k] = h;
        jb.Wlo[(size_t)n * jb.Kp + k] = f2bf(v - bf2f(h));
    }
}

// ---------------- softmax weights -> packed meta {src, w0, w1, 0} (L1/L2) ----------
// One wave per dst node. Register-cached logits (avg degree ~17 < 64 lanes).
__global__ __launch_bounds__(256) void attn_meta(
    const float* __restrict__ al_s, const float* __restrict__ al_d,
    const int* __restrict__ indptr, const int* __restrict__ csr_src,
    float4* __restrict__ meta, int Nn)
{
    int wave = threadIdx.x >> 6, lane = threadIdx.x & 63;
    int i = blockIdx.x * 4 + wave;
    if (i >= Nn) return;
    int start = indptr[i], end = indptr[i + 1];
    float ad0 = al_d[2 * i], ad1 = al_d[2 * i + 1];

    int j0 = start + lane;
    int sreg = 0;
    float e0r = 0.f, e1r = 0.f;
    float m0 = -1e30f, m1 = -1e30f, den0 = 0.f, den1 = 0.f;
    if (j0 < end) {
        sreg = csr_src[j0];
        float2 as = *(const float2*)(al_s + 2 * sreg);
        e0r = as.x + ad0; e0r = e0r > 0.f ? e0r : NEG_SLOPE * e0r;
        e1r = as.y + ad1; e1r = e1r > 0.f ? e1r : NEG_SLOPE * e1r;
        m0 = e0r; den0 = 1.f;
        m1 = e1r; den1 = 1.f;
    }
    for (int j = j0 + 64; j < end; j += 64) {      // rare: deg > 64
        int s = csr_src[j];
        float2 as = *(const float2*)(al_s + 2 * s);
        float e0 = as.x + ad0; e0 = e0 > 0.f ? e0 : NEG_SLOPE * e0;
        float e1 = as.y + ad1; e1 = e1 > 0.f ? e1 : NEG_SLOPE * e1;
        float n0 = fmaxf(m0, e0);
        den0 = den0 * __expf(m0 - n0) + __expf(e0 - n0);
        m0 = n0;
        float n1 = fmaxf(m1, e1);
        den1 = den1 * __expf(m1 - n1) + __expf(e1 - n1);
        m1 = n1;
    }
#pragma unroll
    for (int off = 32; off; off >>= 1) {
        float mo0 = __shfl_xor(m0, off), do0 = __shfl_xor(den0, off);
        float n0 = fmaxf(m0, mo0);
        den0 = den0 * __expf(m0 - n0) + do0 * __expf(mo0 - n0);
        m0 = n0;
        float mo1 = __shfl_xor(m1, off), do1 = __shfl_xor(den1, off);
        float n1 = fmaxf(m1, mo1);
        den1 = den1 * __expf(m1 - n1) + do1 * __expf(mo1 - n1);
        m1 = n1;
    }
    float inv0 = 1.f / den0, inv1 = 1.f / den1;
    if (j0 < end) {
        float4 md;
        md.x = __int_as_float(sreg);
        md.y = __expf(e0r - m0) * inv0;
        md.z = __expf(e1r - m1) * inv1;
        md.w = 0.f;
        meta[j0] = md;
    }
    for (int j = j0 + 64; j < end; j += 64) {      // rare tail
        int s = csr_src[j];
        float2 as = *(const float2*)(al_s + 2 * s);
        float e0 = as.x + ad0; e0 = e0 > 0.f ? e0 : NEG_SLOPE * e0;
        float e1 = as.y + ad1; e1 = e1 > 0.f ? e1 : NEG_SLOPE * e1;
        float4 md;
        md.x = __int_as_float(s);
        md.y = __expf(e0 - m0) * inv0;
        md.z = __expf(e1 - m1) * inv1;
        md.w = 0.f;
        meta[j] = md;
    }
}

// ---------------- per-node softmax stats {m0, 1/den0, m1, 1/den1} (L3/L4) --------
__global__ __launch_bounds__(256) void attn_stats(
    const float* __restrict__ al_s, const float* __restrict__ al_d,
    const int* __restrict__ indptr, const int* __restrict__ csr_src,
    float4* __restrict__ stats, int Nn)
{
    int wave = threadIdx.x >> 6, lane = threadIdx.x & 63;
    int i = blockIdx.x * 4 + wave;
    if (i >= Nn) return;
    int start = indptr[i], end = indptr[i + 1];
    float ad0 = al_d[2 * i], ad1 = al_d[2 * i + 1];

    float m0 = -1e30f, m1 = -1e30f, den0 = 0.f, den1 = 0.f;
    for (int j = start + lane; j < end; j += 64) {
        int s = csr_src[j];
        float2 as = *(const float2*)(al_s + 2 * s);
        float e0 = as.x + ad0; e0 = e0 > 0.f ? e0 : NEG_SLOPE * e0;
        float e1 = as.y + ad1; e1 = e1 > 0.f ? e1 : NEG_SLOPE * e1;
        float n0 = fmaxf(m0, e0);
        den0 = den0 * __expf(m0 - n0) + __expf(e0 - n0);
        m0 = n0;
        float n1 = fmaxf(m1, e1);
        den1 = den1 * __expf(m1 - n1) + __expf(e1 - n1);
        m1 = n1;
    }
#pragma unroll
    for (int off = 32; off; off >>= 1) {
        float mo0 = __shfl_xor(m0, off), do0 = __shfl_xor(den0, off);
        float n0 = fmaxf(m0, mo0);
        den0 = den0 * __expf(m0 - n0) + do0 * __expf(mo0 - n0);
        m0 = n0;
        float mo1 = __shfl_xor(m1, off), do1 = __shfl_xor(den1, off);
        float n1 = fmaxf(m1, mo1);
        den1 = den1 * __expf(m1 - n1) + do1 * __expf(mo1 - n1);
        m1 = n1;
    }
    if (lane == 0)
        stats[i] = make_float4(m0, 1.f / den0, m1, 1.f / den1);
}

// ------- gather (meta path, L1/L2): out[i]=sum_j w_j*h[src_j] -> bf16 hi/lo -------
template<int LPE, int NCH>
__global__ __launch_bounds__(256) void gat_gather(
    const float* __restrict__ hlin, const float4* __restrict__ meta,
    const int* __restrict__ indptr, const float* __restrict__ bias,
    unsigned short* __restrict__ outHi, unsigned short* __restrict__ outLo,
    int ldo, int i0, int Nn, int C, int HC, int HCpad)
{
    constexpr int G = 64 / LPE;
    const int wave = threadIdx.x >> 6, lane = threadIdx.x & 63;
    const int slot = blockIdx.x * 4 + wave;
    const int i = i0 + slot / NCH;
    const int chunk = slot % NCH;
    if (i >= Nn) return;
    const int l = lane % LPE;
    const int g = lane / LPE;
    const int ch4 = chunk * LPE * 4 + l * 4;
    const bool chA = ch4 < HCpad;
    const int start = indptr[i], end = indptr[i + 1];

    float a0 = 0.f, a1 = 0.f, a2 = 0.f, a3 = 0.f;
    const bool h0 = (ch4 + 0) < C, h1 = (ch4 + 1) < C,
               h2 = (ch4 + 2) < C, h3 = (ch4 + 3) < C;

    for (int jb = start; jb < end; jb += 4 * G) {
#pragma unroll
        for (int u = 0; u < 4; ++u) {
            int j = jb + u * G + g;
            int jj = j < end ? j : end - 1;   // end-1 >= start (self-loop)
            float4 md = meta[jj];
            int s = __float_as_int(md.x);
            float w0 = md.y, w1 = md.z;
            if (j >= end) { w0 = 0.f; w1 = 0.f; }
            const float* hr = hlin + (size_t)s * HCpad;
            float4 h = chA ? *(const float4*)(hr + ch4)
                           : make_float4(0.f, 0.f, 0.f, 0.f);
            a0 = fmaf(h0 ? w0 : w1, h.x, a0);
            a1 = fmaf(h1 ? w0 : w1, h.y, a1);
            a2 = fmaf(h2 ? w0 : w1, h.z, a2);
            a3 = fmaf(h3 ? w0 : w1, h.w, a3);
        }
    }
#pragma unroll
    for (int off = LPE; off < 64; off <<= 1) {
        a0 += __shfl_xor(a0, off);
        a1 += __shfl_xor(a1, off);
        a2 += __shfl_xor(a2, off);
        a3 += __shfl_xor(a3, off);
    }
    if (g == 0 && chA) {
        float bx = (ch4 + 0 < HC) ? bias[ch4 + 0] : 0.f;
        float by = (ch4 + 1 < HC) ? bias[ch4 + 1] : 0.f;
        float bz = (ch4 + 2 < HC) ? bias[ch4 + 2] : 0.f;
        float bw = (ch4 + 3 < HC) ? bias[ch4 + 3] : 0.f;
        float v0 = fmaxf(a0 + bx, 0.f);
        float v1 = fmaxf(a1 + by, 0.f);
        float v2 = fmaxf(a2 + bz, 0.f);
        float v3 = fmaxf(a3 + bw, 0.f);
        ushort4 h, lo;
        h.x = f2bf(v0); lo.x = f2bf(v0 - bf2f(h.x));
        h.y = f2bf(v1); lo.y = f2bf(v1 - bf2f(h.y));
        h.z = f2bf(v2); lo.z = f2bf(v2 - bf2f(h.z));
        h.w = f2bf(v3); lo.w = f2bf(v3 - bf2f(h.w));
        *(ushort4*)(outHi + (size_t)i * ldo + ch4) = h;
        *(ushort4*)(outLo + (size_t)i * ldo + ch4) = lo;
    }
    if (chunk == 0) {
        for (int z = HCpad + lane * 4; z < ldo; z += 256) {
            ushort4 zz; zz.x = zz.y = zz.z = zz.w = 0;
            *(ushort4*)(outHi + (size_t)i * ldo + z) = zz;
            *(ushort4*)(outLo + (size_t)i * ldo + z) = zz;
        }
    }
}

// ------- gather (inline-stats path, L3/L4, NCH=1): weights computed in-loop -------
template<int LPE>
__global__ __launch_bounds__(256) void gat_gather_inl(
    const float* __restrict__ hlin,
    const float* __restrict__ al_s, const float* __restrict__ al_d,
    const float4* __restrict__ stats,
    const int* __restrict__ indptr, const int* __restrict__ csr_src,
    const float* __restrict__ bias,
    unsigned short* __restrict__ outHi, unsigned short* __restrict__ outLo,
    int ldo, int Nn, int C, int HC, int HCpad)
{
    constexpr int G = 64 / LPE;
    const int wave = threadIdx.x >> 6, lane = threadIdx.x & 63;
    const int i = blockIdx.x * 4 + wave;
    if (i >= Nn) return;
    const int l = lane % LPE;
    const int g = lane / LPE;
    const int ch4 = l * 4;
    const bool chA = ch4 < HCpad;
    const int start = indptr[i], end = indptr[i + 1];
    const float ad0 = al_d[2 * i], ad1 = al_d[2 * i + 1];
    const float4 st = stats[i];
    const float m0 = st.x, inv0 = st.y, m1 = st.z, inv1 = st.w;

    float a0 = 0.f, a1 = 0.f, a2 = 0.f, a3 = 0.f;
    const bool h0 = (ch4 + 0) < C, h1 = (ch4 + 1) < C,
               h2 = (ch4 + 2) < C, h3 = (ch4 + 3) < C;

    for (int jb = start; jb < end; jb += 4 * G) {
#pragma unroll
        for (int u = 0; u < 4; ++u) {
            int j = jb + u * G + g;
            int jj = j < end ? j : end - 1;   // end-1 >= start (self-loop)
            int s = csr_src[jj];
            float2 as = *(const float2*)(al_s + 2 * s);
            float e0 = as.x + ad0; e0 = e0 > 0.f ? e0 : NEG_SLOPE * e0;
            float e1 = as.y + ad1; e1 = e1 > 0.f ? e1 : NEG_SLOPE * e1;
            float w0 = __expf(e0 - m0) * inv0;
            float w1 = __expf(e1 - m1) * inv1;
            if (j >= end) { w0 = 0.f; w1 = 0.f; }
            const float* hr = hlin + (size_t)s * HCpad;
            float4 h = chA ? *(const float4*)(hr + ch4)
                           : make_float4(0.f, 0.f, 0.f, 0.f);
            a0 = fmaf(h0 ? w0 : w1, h.x, a0);
            a1 = fmaf(h1 ? w0 : w1, h.y, a1);
            a2 = fmaf(h2 ? w0 : w1, h.z, a2);
            a3 = fmaf(h3 ? w0 : w1, h.w, a3);
        }
    }
#pragma unroll
    for (int off = LPE; off < 64; off <<= 1) {
        a0 += __shfl_xor(a0, off);
        a1 += __shfl_xor(a1, off);
        a2 += __shfl_xor(a2, off);
        a3 += __shfl_xor(a3, off);
    }
    if (g == 0 && chA) {
        float bx = (ch4 + 0 < HC) ? bias[ch4 + 0] : 0.f;
        float by = (ch4 + 1 < HC) ? bias[ch4 + 1] : 0.f;
        float bz = (ch4 + 2 < HC) ? bias[ch4 + 2] : 0.f;
        float bw = (ch4 + 3 < HC) ? bias[ch4 + 3] : 0.f;
        float v0 = fmaxf(a0 + bx, 0.f);
        float v1 = fmaxf(a1 + by, 0.f);
        float v2 = fmaxf(a2 + bz, 0.f);
        float v3 = fmaxf(a3 + bw, 0.f);
        ushort4 h, lo;
        h.x = f2bf(v0); lo.x = f2bf(v0 - bf2f(h.x));
        h.y = f2bf(v1); lo.y = f2bf(v1 - bf2f(h.y));
        h.z = f2bf(v2); lo.z = f2bf(v2 - bf2f(h.z));
        h.w = f2bf(v3); lo.w = f2bf(v3 - bf2f(h.w));
        *(ushort4*)(outHi + (size_t)i * ldo + ch4) = h;
        *(ushort4*)(outLo + (size_t)i * ldo + ch4) = lo;
    }
    for (int z = HCpad + lane * 4; z < ldo; z += 256) {
        ushort4 zz; zz.x = zz.y = zz.z = zz.w = 0;
        *(ushort4*)(outHi + (size_t)i * ldo + z) = zz;
        *(ushort4*)(outLo + (size_t)i * ldo + z) = zz;
    }
}

// ---------------- CSR build (with self-loops folded in) ----------------
__global__ void hist_self_k(const int* __restrict__ dst, int E,
                            int* __restrict__ counts, int n)
{
    int gid = blockIdx.x * blockDim.x + threadIdx.x;
    if (gid < E) atomicAdd(&counts[dst[gid]], 1);
    else if (gid < E + n) atomicAdd(&counts[gid - E], 1);
}

__global__ void scan_block_k(const int* __restrict__ in, int* __restrict__ out,
                             int* __restrict__ bsum, int n)
{
    __shared__ int sh[256];
    int gid = blockIdx.x * 256 + threadIdx.x;
    int v = (gid < n) ? in[gid] : 0;
    sh[threadIdx.x] = v;
    __syncthreads();
    for (int off = 1; off < 256; off <<= 1) {
        int t = (threadIdx.x >= off) ? sh[threadIdx.x - off] : 0;
        __syncthreads();
        sh[threadIdx.x] += t;
        __syncthreads();
    }
    int incl = sh[threadIdx.x];
    if (gid < n) out[gid] = incl - v;
    if (threadIdx.x == 255) bsum[blockIdx.x] = incl;
}

__global__ void scan_tops_k(const int* __restrict__ bsum, int* __restrict__ boff)
{
    __shared__ int sh[256];
    int v = bsum[threadIdx.x];
    sh[threadIdx.x] = v;
    __syncthreads();
    for (int off = 1; off < 256; off <<= 1) {
        int t = (threadIdx.x >= off) ? sh[threadIdx.x - off] : 0;
        __syncthreads();
        sh[threadIdx.x] += t;
        __syncthreads();
    }
    boff[threadIdx.x] = sh[threadIdx.x] - v;
}

__global__ void scan_add_k(int* __restrict__ indptr, const int* __restrict__ boff,
                           int n, int Etot)
{
    int gid = blockIdx.x * 256 + threadIdx.x;
    if (gid < n) indptr[gid] += boff[blockIdx.x];
    if (gid == 0) indptr[n] = Etot;
}

__global__ void fill_k(const int* __restrict__ src, const int* __restrict__ dst, int E,
                       const int* __restrict__ indptr, int* __restrict__ cursor,
                       int* __restrict__ csr_src)
{
    int e = blockIdx.x * blockDim.x + threadIdx.x;
    if (e < E) {
        int d = dst[e];
        int pos = atomicAdd(&cursor[d], 1);
        csr_src[indptr[d] + pos] = src[e];
    }
}

__global__ void fill_self_k(const int* __restrict__ indptr, int* __restrict__ cursor,
                            int* __restrict__ csr_src, int n)
{
    int i = blockIdx.x * blockDim.x + threadIdx.x;
    if (i < n) {
        int pos = atomicAdd(&cursor[i], 1);
        csr_src[indptr[i] + pos] = i;
    }
}

// ---------------- launch ----------------
extern "C" void kernel_launch(void* const* d_in, const int* in_sizes, int n_in,
                              void* d_out, int out_size, void* d_ws, size_t ws_size,
                              hipStream_t stream)
{
    (void)in_sizes; (void)n_in; (void)out_size; (void)ws_size;
    const int N = N_NODES;
    const int E = N_EDGES;
    const int Etot = E + N;

    const float* x = (const float*)d_in[0];
    const int* ei = (const int*)d_in[1];
    const float* Wc[4] = {(const float*)d_in[3], (const float*)d_in[7],
                          (const float*)d_in[11], (const float*)d_in[15]};
    const float* AS[4] = {(const float*)d_in[4], (const float*)d_in[8],
                          (const float*)d_in[12], (const float*)d_in[16]};
    const float* AD[4] = {(const float*)d_in[5], (const float*)d_in[9],
                          (const float*)d_in[13], (const float*)d_in[17]};
    const float* Bc[4] = {(const float*)d_in[6], (const float*)d_in[10],
                          (const float*)d_in[14], (const float*)d_in[18]};
    const float* LW[4] = {(const float*)d_in[19], (const float*)d_in[21],
                          (const float*)d_in[23], (const float*)d_in[25]};
    const float* LB[4] = {(const float*)d_in[20], (const float*)d_in[22],
                          (const float*)d_in[24], (const float*)d_in[26]};

    char* w = (char*)d_ws;
    auto alloc = [&](size_t bytes) -> char* {
        char* p = w; w += (bytes + 255) & ~(size_t)255; return p;
    };
    float* bufC = (float*)alloc((size_t)N * 252 * 4);            // GEMM out, fp32
    unsigned short* actHi = (unsigned short*)alloc((size_t)N * 256 * 2);
    unsigned short* actLo = (unsigned short*)alloc((size_t)N * 256 * 2);
    float4* meta = (float4*)alloc((size_t)Etot * 16);
    float4* stats = (float4*)alloc((size_t)N * 16);
    // MLP intermediates
    unsigned short* mlp1Hi = (unsigned short*)alloc((size_t)8192 * 224 * 2);
    unsigned short* mlp1Lo = (unsigned short*)alloc((size_t)8192 * 224 * 2);
    unsigned short* mlp2Hi = (unsigned short*)alloc((size_t)8192 * 128 * 2);
    unsigned short* mlp2Lo = (unsigned short*)alloc((size_t)8192 * 128 * 2);
    unsigned short* mlp3Hi = (unsigned short*)alloc((size_t)8192 * 128 * 2);
    unsigned short* mlp3Lo = (unsigned short*)alloc((size_t)8192 * 128 * 2);
    int* csr    = (int*)alloc((size_t)Etot * 4);
    float* alSD = (float*)alloc((size_t)N * 4 * 4 * 4);  // 4 layers x [alS|alD]
    int* cnt2   = (int*)alloc((size_t)N * 2 * 4);        // counts then cursor
    int* counts = cnt2;
    int* cursor = cnt2 + N;
    int* indptr = (int*)alloc((size_t)(N + 8) * 4);
    int* bsum   = (int*)alloc(1024);
    int* boff   = (int*)alloc(1024);

    const int KpConv[4] = {352, 256, 160, 128};
    const int NpConv[4] = {256, 192, 128, 64};
    const int KpLin[4]  = {512, 224, 128, 128};
    const int NpLin[4]  = {256, 128, 128, 64};
    unsigned short *WtHi[4], *WtLo[4], *LtHi[4], *LtLo[4];
    for (int l = 0; l < 4; ++l) {
        WtHi[l] = (unsigned short*)alloc((size_t)NpConv[l] * KpConv[l] * 2);
        WtLo[l] = (unsigned short*)alloc((size_t)NpConv[l] * KpConv[l] * 2);
    }
    for (int l = 0; l < 4; ++l) {
        LtHi[l] = (unsigned short*)alloc((size_t)NpLin[l] * KpLin[l] * 2);
        LtLo[l] = (unsigned short*)alloc((size_t)NpLin[l] * KpLin[l] * 2);
    }

    const int* esrc = ei;
    const int* edst = ei + E;

    // ---- CSR by dst incl. self-loops; zero all 4 layers' al buffers upfront ----
    hipMemsetAsync(cnt2, 0, (size_t)N * 2 * 4, stream);
    hipMemsetAsync(alSD, 0, (size_t)N * 4 * 4 * 4, stream);
    hist_self_k<<<(E + N) / 256, 256, 0, stream>>>(edst, E, counts, N);
    scan_block_k<<<N / 256, 256, 0, stream>>>(counts, indptr, bsum, N);
    scan_tops_k<<<1, 256, 0, stream>>>(bsum, boff);
    scan_add_k<<<N / 256, 256, 0, stream>>>(indptr, boff, N, Etot);
    fill_k<<<E / 256, 256, 0, stream>>>(esrc, edst, E, indptr, cursor, csr);
    fill_self_k<<<N / 256, 256, 0, stream>>>(indptr, cursor, csr, N);

    // ---- weight decompose (one kernel for all 8) ----
    const int Kc[4] = {336, 250, 150, 100}, Nc[4] = {250, 150, 100, 60};
    const int Kl[4] = {480, 200, 100, 100}, Nl[4] = {200, 100, 100, 29};
    WtJobs jobs;
    int nb = 0;
    for (int l = 0; l < 4; ++l) {
        jobs.j[l] = {Wc[l], WtHi[l], WtLo[l], Kc[l], Nc[l], KpConv[l], 0, nb};
        nb += NpConv[l];
    }
    for (int l = 0; l < 4; ++l) {
        jobs.j[4 + l] = {LW[l], LtHi[l], LtLo[l], Kl[l], Nl[l], KpLin[l],
                         l == 0 ? 1 : 0, nb};
        nb += NpLin[l];
    }
    wt_decomp_all<<<nb, 256, 0, stream>>>(jobs);

    // ---- 4 GAT layers ----
    const int HCp[4]  = {252, 152, 100, 60};   // fp32 GEMM-out leading dim
    const int ldoA[4] = {256, 160, 128, 64};   // bf16 act leading dim (= next Kp)
    const int ldaA[4] = {336, 256, 160, 128};  // A leading dim into GEMM
    for (int l = 0; l < 4; ++l) {
        int C = Nc[l] / 2, HC = Nc[l];
        float* alS = alSD + (size_t)l * N * 4;
        float* alD = alS + (size_t)N * 2;
        if (l == 0) {
            gemm_mfma<128><<<dim3(2, N / 128), 256, 0, stream>>>(
                x, 336, nullptr, nullptr, 336, 352,
                WtHi[0], WtLo[0], nullptr, 0,
                bufC, nullptr, nullptr, HCp[0], HCp[0], 0,
                AS[0], AD[0], alS, alD, C, HC);
        } else if (l == 1) {
            gemm_mfma<64><<<dim3(3, N / 128), 256, 0, stream>>>(
                nullptr, 0, actHi, actLo, ldaA[1], KpConv[1],
                WtHi[1], WtLo[1], nullptr, 0,
                bufC, nullptr, nullptr, HCp[1], HCp[1], 0,
                AS[1], AD[1], alS, alD, C, HC);
        } else if (l == 2) {
            gemm_mfma<128><<<dim3(1, N / 128), 256, 0, stream>>>(
                nullptr, 0, actHi, actLo, ldaA[2], KpConv[2],
                WtHi[2], WtLo[2], nullptr, 0,
                bufC, nullptr, nullptr, HCp[2], HCp[2], 0,
                AS[2], AD[2], alS, alD, C, HC);
        } else {
            gemm_mfma<64><<<dim3(1, N / 128), 256, 0, stream>>>(
                nullptr, 0, actHi, actLo, ldaA[3], KpConv[3],
                WtHi[3], WtLo[3], nullptr, 0,
                bufC, nullptr, nullptr, HCp[3], HCp[3], 0,
                AS[3], AD[3], alS, alD, C, HC);
        }
        if (l == 0) {
            attn_meta<<<N / 4, 256, 0, stream>>>(alS, alD, indptr, csr, meta, N);
            // split into two half-node dispatches (unmask tier-2 in profile)
            gat_gather<32, 2><<<N / 4, 256, 0, stream>>>(
                bufC, meta, indptr, Bc[0],
                actHi, actLo, ldoA[0], 0, N, C, HC, HCp[0]);
            gat_gather<32, 2><<<N / 4, 256, 0, stream>>>(
                bufC, meta, indptr, Bc[0],
                actHi, actLo, ldoA[0], N / 2, N, C, HC, HCp[0]);
        } else if (l == 1) {
            attn_meta<<<N / 4, 256, 0, stream>>>(alS, alD, indptr, csr, meta, N);
            gat_gather<16, 3><<<N * 3 / 4, 256, 0, stream>>>(
                bufC, meta, indptr, Bc[1],
                actHi, actLo, ldoA[1], 0, N, C, HC, HCp[1]);
        } else if (l == 2) {
            attn_stats<<<N / 4, 256, 0, stream>>>(alS, alD, indptr, csr, stats, N);
            gat_gather_inl<32><<<N / 4, 256, 0, stream>>>(
                bufC, alS, alD, stats, indptr, csr, Bc[2],
                actHi, actLo, ldoA[2], N, C, HC, HCp[2]);
        } else {
            attn_stats<<<N / 4, 256, 0, stream>>>(alS, alD, indptr, csr, stats, N);
            gat_gather_inl<16><<<N / 4, 256, 0, stream>>>(
                bufC, alS, alD, stats, indptr, csr, Bc[3],
                actHi, actLo, ldoA[3], N, C, HC, HCp[3]);
        }
    }

    // ---- MLP head: [8192,480(512 remapped)] -> 200 -> 100 -> 100 -> 29 ----
    gemm_mfma<128><<<dim3(2, 64), 256, 0, stream>>>(
        nullptr, 0, actHi, actLo, 512, 512,
        LtHi[0], LtLo[0], LB[0], 200,
        nullptr, mlp1Hi, mlp1Lo, 224, 224, 1,
        nullptr, nullptr, nullptr, nullptr, 0, 0);
    gemm_mfma<128><<<dim3(1, 64), 256, 0, stream>>>(
        nullptr, 0, mlp1Hi, mlp1Lo, 224, 224,
        LtHi[1], LtLo[1], LB[1], 100,
        nullptr, mlp2Hi, mlp2Lo, 128, 128, 1,
        nullptr, nullptr, nullptr, nullptr, 0, 0);
    gemm_mfma<128><<<dim3(1, 64), 256, 0, stream>>>(
        nullptr, 0, mlp2Hi, mlp2Lo, 128, 128,
        LtHi[2], LtLo[2], LB[2], 100,
        nullptr, mlp3Hi, mlp3Lo, 128, 128, 1,
        nullptr, nullptr, nullptr, nullptr, 0, 0);
    gemm_mfma<64><<<dim3(1, 64), 256, 0, stream>>>(
        nullptr, 0, mlp3Hi, mlp3Lo, 128, 128,
        LtHi[3], LtLo[3], LB[3], 29,
        (float*)d_out, nullptr, nullptr, 29, 29, 0,
        nullptr, nullptr, nullptr, nullptr, 0, 0);
}

// Round 9
// 1039.497 us; speedup vs baseline: 1.0463x; 1.0463x over previous
//
#include <hip/hip_runtime.h>
#include <hip/hip_bf16.h>
#include <stdint.h>

#define N_NODES 65536
#define N_EDGES (N_NODES * 16)
#define NEG_SLOPE 0.2f

typedef short bf16x8 __attribute__((ext_vector_type(8)));   // 8 bf16 in 4 VGPRs
typedef float f32x4 __attribute__((ext_vector_type(4)));

__device__ __forceinline__ unsigned short f2bf(float f) {
    unsigned u = __float_as_uint(f);
    u += 0x7fffu + ((u >> 16) & 1u);       // RNE
    return (unsigned short)(u >> 16);
}
__device__ __forceinline__ float bf2f(unsigned short h) {
    return __uint_as_float(((unsigned)h) << 16);
}
__device__ __forceinline__ void load_lds16(const void* g, void* l) {
    __builtin_amdgcn_global_load_lds(
        (const __attribute__((address_space(1))) unsigned int*)g,
        (__attribute__((address_space(3))) unsigned int*)l, 16, 0, 0);
}

// ---------------- MFMA GEMM: C[M,Nw] = A[M,Kp] @ Wt^T (+bias,+relu) ----------------
// A: fp32 (A32 path, converted during staging) or bf16 hi/lo pair.
// Wt transposed [n][Kp] bf16 hi/lo, zero-padded.
// Split-bf16: acc += Ahi*Bhi + Alo*Bhi + Ahi*Blo  (fp32 MFMA accumulate).
// Block 256 = 4 waves; tile 128(M) x TN(N), TN in {64,128}; BK=32.
// If asrc != null: also computes per-row attention dots al_s/al_d (atomicAdd).
template<int TN>
__global__ __launch_bounds__(256) void gemm_mfma(
    const float* __restrict__ A32, int KA,
    const unsigned short* __restrict__ Ahi, const unsigned short* __restrict__ Alo,
    int lda, int Kp,
    const unsigned short* __restrict__ Bhi, const unsigned short* __restrict__ Blo,
    const float* __restrict__ bias, int Nbias,
    float* __restrict__ C32,
    unsigned short* __restrict__ Chi, unsigned short* __restrict__ Clo,
    int ldc, int Nw, int relu,
    const float* __restrict__ asrc, const float* __restrict__ adst,
    float* __restrict__ alS, float* __restrict__ alD, int Cal, int HCal)
{
    constexpr int NI = TN / 32;                 // N-frags per wave
    __shared__ unsigned short sAhi[128 * 32], sAlo[128 * 32];
    __shared__ unsigned short sBhi[TN * 32],  sBlo[TN * 32];
    __shared__ float sAl[128][2][4];
    const int tid = threadIdx.x;
    const int wave = tid >> 6, lane = tid & 63;
    const int row0 = blockIdx.y * 128;
    const int col0 = blockIdx.x * TN;
    const int wm = (wave & 1) * 64, wn = (wave >> 1) * (TN / 2);
    const int mlane = lane & 15, q = lane >> 4;

    f32x4 acc[4][NI];
#pragma unroll
    for (int a = 0; a < 4; ++a)
#pragma unroll
        for (int b = 0; b < NI; ++b) acc[a][b] = (f32x4){0.f, 0.f, 0.f, 0.f};

    for (int k0 = 0; k0 < Kp; k0 += 32) {
        __syncthreads();
        if (A32) {
            // fp32 -> bf16 hi/lo conversion staging (layer 1 only)
            const int r = tid >> 1, cbase = (tid & 1) * 16;
            const float* Ap = A32 + (size_t)(row0 + r) * lda;
#pragma unroll
            for (int j = 0; j < 4; ++j) {
                int kc = k0 + cbase + j * 4;
                float4 v = make_float4(0.f, 0.f, 0.f, 0.f);
                if (kc < KA) v = *(const float4*)(Ap + kc);
                ushort4 h, l;
                h.x = f2bf(v.x); l.x = f2bf(v.x - bf2f(h.x));
                h.y = f2bf(v.y); l.y = f2bf(v.y - bf2f(h.y));
                h.z = f2bf(v.z); l.z = f2bf(v.z - bf2f(h.z));
                h.w = f2bf(v.w); l.w = f2bf(v.w - bf2f(h.w));
                *(ushort4*)(sAhi + r * 32 + cbase + j * 4) = h;
                *(ushort4*)(sAlo + r * 32 + cbase + j * 4) = l;
            }
        } else {
            // async global->LDS, 16B/lane; LDS dst = wave-uniform base + lane*16
#pragma unroll
            for (int cc = 0; cc < 2; ++cc) {
                int c = wave * 2 + cc;                 // 8 chunks of 16 rows
                int r = c * 16 + (lane >> 2);
                size_t goff = (size_t)(row0 + r) * lda + k0 + (lane & 3) * 8;
                load_lds16(Ahi + goff, sAhi + c * 512);
                load_lds16(Alo + goff, sAlo + c * 512);
            }
        }
        {
#pragma unroll
            for (int cc = 0; cc < TN / 64; ++cc) {
                int c = wave * (TN / 64) + cc;         // TN/16 chunks of 16 rows
                int r = c * 16 + (lane >> 2);
                size_t goff = (size_t)(col0 + r) * Kp + k0 + (lane & 3) * 8;
                load_lds16(Bhi + goff, sBhi + c * 512);
                load_lds16(Blo + goff, sBlo + c * 512);
            }
        }
        __syncthreads();

        bf16x8 ah[4], al[4], bh[NI], bl[NI];
#pragma unroll
        for (int mi = 0; mi < 4; ++mi) {
            int m = wm + mi * 16 + mlane;
            ah[mi] = *(const bf16x8*)(sAhi + m * 32 + q * 8);
            al[mi] = *(const bf16x8*)(sAlo + m * 32 + q * 8);
        }
#pragma unroll
        for (int ni = 0; ni < NI; ++ni) {
            int n = wn + ni * 16 + mlane;
            bh[ni] = *(const bf16x8*)(sBhi + n * 32 + q * 8);
            bl[ni] = *(const bf16x8*)(sBlo + n * 32 + q * 8);
        }
#pragma unroll
        for (int mi = 0; mi < 4; ++mi)
#pragma unroll
            for (int ni = 0; ni < NI; ++ni) {
                acc[mi][ni] = __builtin_amdgcn_mfma_f32_16x16x32_bf16(ah[mi], bh[ni], acc[mi][ni], 0, 0, 0);
                acc[mi][ni] = __builtin_amdgcn_mfma_f32_16x16x32_bf16(al[mi], bh[ni], acc[mi][ni], 0, 0, 0);
                acc[mi][ni] = __builtin_amdgcn_mfma_f32_16x16x32_bf16(ah[mi], bl[ni], acc[mi][ni], 0, 0, 0);
            }
    }

    // epilogue: C/D frag layout col=lane&15, row=(lane>>4)*4+reg
#pragma unroll
    for (int ni = 0; ni < NI; ++ni) {
        int col = col0 + wn + ni * 16 + mlane;
        if (col >= Nw) continue;
        float bv = (bias && col < Nbias) ? bias[col] : 0.f;
#pragma unroll
        for (int mi = 0; mi < 4; ++mi) {
#pragma unroll
            for (int reg = 0; reg < 4; ++reg) {
                int row = row0 + wm + mi * 16 + q * 4 + reg;
                float v = acc[mi][ni][reg] + bv;
                if (relu) v = fmaxf(v, 0.f);
                size_t off = (size_t)row * ldc + col;
                if (Chi) {
                    unsigned short h = f2bf(v);
                    Chi[off] = h;
                    Clo[off] = f2bf(v - bf2f(h));
                } else {
                    C32[off] = v;
                }
            }
        }
    }

    // fused attention-logit dots: al_s[row,h] += sum_c h[row,c]*a_s[h,c], same for a_d
    if (asrc) {
        float asv[NI], adv[NI];
        bool head0[NI];
#pragma unroll
        for (int ni = 0; ni < NI; ++ni) {
            int col = col0 + wn + ni * 16 + mlane;
            bool valid = col < HCal;
            head0[ni] = col < Cal;
            asv[ni] = valid ? asrc[col] : 0.f;
            adv[ni] = valid ? adst[col] : 0.f;
        }
#pragma unroll
        for (int mi = 0; mi < 4; ++mi) {
#pragma unroll
            for (int reg = 0; reg < 4; ++reg) {
                float s0 = 0.f, s1 = 0.f, d0 = 0.f, d1 = 0.f;
#pragma unroll
                for (int ni = 0; ni < NI; ++ni) {
                    float v = acc[mi][ni][reg];
                    if (head0[ni]) { s0 += v * asv[ni]; d0 += v * adv[ni]; }
                    else           { s1 += v * asv[ni]; d1 += v * adv[ni]; }
                }
#pragma unroll
                for (int off = 1; off < 16; off <<= 1) {
                    s0 += __shfl_xor(s0, off); s1 += __shfl_xor(s1, off);
                    d0 += __shfl_xor(d0, off); d1 += __shfl_xor(d1, off);
                }
                if (mlane == 0) {
                    int rl = wm + mi * 16 + q * 4 + reg;
                    int slot = wave >> 1;
                    sAl[rl][slot][0] = s0; sAl[rl][slot][1] = s1;
                    sAl[rl][slot][2] = d0; sAl[rl][slot][3] = d1;
                }
            }
        }
        __syncthreads();
        if (tid < 128) {
            int row = row0 + tid;
            float v0 = sAl[tid][0][0] + sAl[tid][1][0];
            float v1 = sAl[tid][0][1] + sAl[tid][1][1];
            float v2 = sAl[tid][0][2] + sAl[tid][1][2];
            float v3 = sAl[tid][0][3] + sAl[tid][1][3];
            atomicAdd(&alS[row * 2 + 0], v0);
            atomicAdd(&alS[row * 2 + 1], v1);
            atomicAdd(&alD[row * 2 + 0], v2);
            atomicAdd(&alD[row * 2 + 1], v3);
        }
    }
}

// ---------------- weight transpose + bf16 hi/lo decompose (all 8 in one) ----------
struct WtJob {
    const float* W; unsigned short* Whi; unsigned short* Wlo;
    int K, N, Kp, remap, nb0;
};
struct WtJobs { WtJob j[8]; };

__global__ void wt_decomp_all(WtJobs jobs)
{
    int b = blockIdx.x;
    int idx = 0;
#pragma unroll
    for (int i = 1; i < 8; ++i)
        if (b >= jobs.j[i].nb0) idx = i;
    WtJob jb = jobs.j[idx];
    int n = b - jb.nb0;
    for (int k = threadIdx.x; k < jb.Kp; k += 256) {
        int ks = k, valid = 1;
        if (jb.remap) {
            int bb = k >> 6, r = k & 63;
            if (r < 60) ks = bb * 60 + r; else valid = 0;
        }
        float v = 0.f;
        if (valid && ks < jb.K && n < jb.N) v = jb.W[(size_t)ks * jb.N + n];
        unsigned short h = f2bf(v);
        jb.Whi[(size_t)n * jb.Kp + k] = h;
        jb.Wlo[(size_t)n * jb.Kp + k] = f2bf(v - bf2f(h));
    }
}

// ---------------- softmax weights -> packed meta {src, w0, w1, 0} (L1/L2) ----------
// One wave per dst node. Register-cached logits (avg degree ~17 < 64 lanes).
__global__ __launch_bounds__(256) void attn_meta(
    const float* __restrict__ al_s, const float* __restrict__ al_d,
    const int* __restrict__ indptr, const int* __restrict__ csr_src,
    float4* __restrict__ meta, int Nn)
{
    int wave = threadIdx.x >> 6, lane = threadIdx.x & 63;
    int i = blockIdx.x * 4 + wave;
    if (i >= Nn) return;
    int start = indptr[i], end = indptr[i + 1];
    float ad0 = al_d[2 * i], ad1 = al_d[2 * i + 1];

    int j0 = start + lane;
    int sreg = 0;
    float e0r = 0.f, e1r = 0.f;
    float m0 = -1e30f, m1 = -1e30f, den0 = 0.f, den1 = 0.f;
    if (j0 < end) {
        sreg = csr_src[j0];
        float2 as = *(const float2*)(al_s + 2 * sreg);
        e0r = as.x + ad0; e0r = e0r > 0.f ? e0r : NEG_SLOPE * e0r;
        e1r = as.y + ad1; e1r = e1r > 0.f ? e1r : NEG_SLOPE * e1r;
        m0 = e0r; den0 = 1.f;
        m1 = e1r; den1 = 1.f;
    }
    for (int j = j0 + 64; j < end; j += 64) {      // rare: deg > 64
        int s = csr_src[j];
        float2 as = *(const float2*)(al_s + 2 * s);
        float e0 = as.x + ad0; e0 = e0 > 0.f ? e0 : NEG_SLOPE * e0;
        float e1 = as.y + ad1; e1 = e1 > 0.f ? e1 : NEG_SLOPE * e1;
        float n0 = fmaxf(m0, e0);
        den0 = den0 * __expf(m0 - n0) + __expf(e0 - n0);
        m0 = n0;
        float n1 = fmaxf(m1, e1);
        den1 = den1 * __expf(m1 - n1) + __expf(e1 - n1);
        m1 = n1;
    }
#pragma unroll
    for (int off = 32; off; off >>= 1) {
        float mo0 = __shfl_xor(m0, off), do0 = __shfl_xor(den0, off);
        float n0 = fmaxf(m0, mo0);
        den0 = den0 * __expf(m0 - n0) + do0 * __expf(mo0 - n0);
        m0 = n0;
        float mo1 = __shfl_xor(m1, off), do1 = __shfl_xor(den1, off);
        float n1 = fmaxf(m1, mo1);
        den1 = den1 * __expf(m1 - n1) + do1 * __expf(mo1 - n1);
        m1 = n1;
    }
    float inv0 = 1.f / den0, inv1 = 1.f / den1;
    if (j0 < end) {
        float4 md;
        md.x = __int_as_float(sreg);
        md.y = __expf(e0r - m0) * inv0;
        md.z = __expf(e1r - m1) * inv1;
        md.w = 0.f;
        meta[j0] = md;
    }
    for (int j = j0 + 64; j < end; j += 64) {      // rare tail
        int s = csr_src[j];
        float2 as = *(const float2*)(al_s + 2 * s);
        float e0 = as.x + ad0; e0 = e0 > 0.f ? e0 : NEG_SLOPE * e0;
        float e1 = as.y + ad1; e1 = e1 > 0.f ? e1 : NEG_SLOPE * e1;
        float4 md;
        md.x = __int_as_float(s);
        md.y = __expf(e0 - m0) * inv0;
        md.z = __expf(e1 - m1) * inv1;
        md.w = 0.f;
        meta[j] = md;
    }
}

// ------- gather (meta path, L1/L2): out[i]=sum_j w_j*h[src_j] -> bf16 hi/lo -------
template<int LPE, int NCH>
__global__ __launch_bounds__(256) void gat_gather(
    const float* __restrict__ hlin, const float4* __restrict__ meta,
    const int* __restrict__ indptr, const float* __restrict__ bias,
    unsigned short* __restrict__ outHi, unsigned short* __restrict__ outLo,
    int ldo, int Nn, int C, int HC, int HCpad)
{
    constexpr int G = 64 / LPE;
    const int wave = threadIdx.x >> 6, lane = threadIdx.x & 63;
    const int slot = blockIdx.x * 4 + wave;
    const int i = slot / NCH;
    const int chunk = slot % NCH;
    if (i >= Nn) return;
    const int l = lane % LPE;
    const int g = lane / LPE;
    const int ch4 = chunk * LPE * 4 + l * 4;
    const bool chA = ch4 < HCpad;
    const int start = indptr[i], end = indptr[i + 1];

    float a0 = 0.f, a1 = 0.f, a2 = 0.f, a3 = 0.f;
    const bool h0 = (ch4 + 0) < C, h1 = (ch4 + 1) < C,
               h2 = (ch4 + 2) < C, h3 = (ch4 + 3) < C;

    for (int jb = start; jb < end; jb += 4 * G) {
#pragma unroll
        for (int u = 0; u < 4; ++u) {
            int j = jb + u * G + g;
            int jj = j < end ? j : end - 1;   // end-1 >= start (self-loop)
            float4 md = meta[jj];
            int s = __float_as_int(md.x);
            float w0 = md.y, w1 = md.z;
            if (j >= end) { w0 = 0.f; w1 = 0.f; }
            const float* hr = hlin + (size_t)s * HCpad;
            float4 h = chA ? *(const float4*)(hr + ch4)
                           : make_float4(0.f, 0.f, 0.f, 0.f);
            a0 = fmaf(h0 ? w0 : w1, h.x, a0);
            a1 = fmaf(h1 ? w0 : w1, h.y, a1);
            a2 = fmaf(h2 ? w0 : w1, h.z, a2);
            a3 = fmaf(h3 ? w0 : w1, h.w, a3);
        }
    }
#pragma unroll
    for (int off = LPE; off < 64; off <<= 1) {
        a0 += __shfl_xor(a0, off);
        a1 += __shfl_xor(a1, off);
        a2 += __shfl_xor(a2, off);
        a3 += __shfl_xor(a3, off);
    }
    if (g == 0 && chA) {
        float bx = (ch4 + 0 < HC) ? bias[ch4 + 0] : 0.f;
        float by = (ch4 + 1 < HC) ? bias[ch4 + 1] : 0.f;
        float bz = (ch4 + 2 < HC) ? bias[ch4 + 2] : 0.f;
        float bw = (ch4 + 3 < HC) ? bias[ch4 + 3] : 0.f;
        float v0 = fmaxf(a0 + bx, 0.f);
        float v1 = fmaxf(a1 + by, 0.f);
        float v2 = fmaxf(a2 + bz, 0.f);
        float v3 = fmaxf(a3 + bw, 0.f);
        ushort4 h, lo;
        h.x = f2bf(v0); lo.x = f2bf(v0 - bf2f(h.x));
        h.y = f2bf(v1); lo.y = f2bf(v1 - bf2f(h.y));
        h.z = f2bf(v2); lo.z = f2bf(v2 - bf2f(h.z));
        h.w = f2bf(v3); lo.w = f2bf(v3 - bf2f(h.w));
        *(ushort4*)(outHi + (size_t)i * ldo + ch4) = h;
        *(ushort4*)(outLo + (size_t)i * ldo + ch4) = lo;
    }
    if (chunk == 0) {
        for (int z = HCpad + lane * 4; z < ldo; z += 256) {
            ushort4 zz; zz.x = zz.y = zz.z = zz.w = 0;
            *(ushort4*)(outHi + (size_t)i * ldo + z) = zz;
            *(ushort4*)(outLo + (size_t)i * ldo + z) = zz;
        }
    }
}

// ------- fused stats+gather (L3/L4, one wave per node): stats in-kernel -------
template<int LPE>
__global__ __launch_bounds__(256) void gat_gather_fused(
    const float* __restrict__ hlin,
    const float* __restrict__ al_s, const float* __restrict__ al_d,
    const int* __restrict__ indptr, const int* __restrict__ csr_src,
    const float* __restrict__ bias,
    unsigned short* __restrict__ outHi, unsigned short* __restrict__ outLo,
    int ldo, int Nn, int C, int HC, int HCpad)
{
    constexpr int G = 64 / LPE;
    const int wave = threadIdx.x >> 6, lane = threadIdx.x & 63;
    const int i = blockIdx.x * 4 + wave;
    if (i >= Nn) return;
    const int start = indptr[i], end = indptr[i + 1];
    const float ad0 = al_d[2 * i], ad1 = al_d[2 * i + 1];

    // phase A: online softmax stats, all 64 lanes strided
    float m0 = -1e30f, m1 = -1e30f, den0 = 0.f, den1 = 0.f;
    for (int j = start + lane; j < end; j += 64) {
        int s = csr_src[j];
        float2 as = *(const float2*)(al_s + 2 * s);
        float e0 = as.x + ad0; e0 = e0 > 0.f ? e0 : NEG_SLOPE * e0;
        float e1 = as.y + ad1; e1 = e1 > 0.f ? e1 : NEG_SLOPE * e1;
        float n0 = fmaxf(m0, e0);
        den0 = den0 * __expf(m0 - n0) + __expf(e0 - n0);
        m0 = n0;
        float n1 = fmaxf(m1, e1);
        den1 = den1 * __expf(m1 - n1) + __expf(e1 - n1);
        m1 = n1;
    }
#pragma unroll
    for (int off = 32; off; off >>= 1) {
        float mo0 = __shfl_xor(m0, off), do0 = __shfl_xor(den0, off);
        float n0 = fmaxf(m0, mo0);
        den0 = den0 * __expf(m0 - n0) + do0 * __expf(mo0 - n0);
        m0 = n0;
        float mo1 = __shfl_xor(m1, off), do1 = __shfl_xor(den1, off);
        float n1 = fmaxf(m1, mo1);
        den1 = den1 * __expf(m1 - n1) + do1 * __expf(mo1 - n1);
        m1 = n1;
    }
    const float inv0 = 1.f / den0, inv1 = 1.f / den1;

    // phase B: weighted gather, inline weights
    const int l = lane % LPE;
    const int g = lane / LPE;
    const int ch4 = l * 4;
    const bool chA = ch4 < HCpad;
    float a0 = 0.f, a1 = 0.f, a2 = 0.f, a3 = 0.f;
    const bool h0 = (ch4 + 0) < C, h1 = (ch4 + 1) < C,
               h2 = (ch4 + 2) < C, h3 = (ch4 + 3) < C;

    for (int jb = start; jb < end; jb += 4 * G) {
#pragma unroll
        for (int u = 0; u < 4; ++u) {
            int j = jb + u * G + g;
            int jj = j < end ? j : end - 1;   // end-1 >= start (self-loop)
            int s = csr_src[jj];
            float2 as = *(const float2*)(al_s + 2 * s);
            float e0 = as.x + ad0; e0 = e0 > 0.f ? e0 : NEG_SLOPE * e0;
            float e1 = as.y + ad1; e1 = e1 > 0.f ? e1 : NEG_SLOPE * e1;
            float w0 = __expf(e0 - m0) * inv0;
            float w1 = __expf(e1 - m1) * inv1;
            if (j >= end) { w0 = 0.f; w1 = 0.f; }
            const float* hr = hlin + (size_t)s * HCpad;
            float4 h = chA ? *(const float4*)(hr + ch4)
                           : make_float4(0.f, 0.f, 0.f, 0.f);
            a0 = fmaf(h0 ? w0 : w1, h.x, a0);
            a1 = fmaf(h1 ? w0 : w1, h.y, a1);
            a2 = fmaf(h2 ? w0 : w1, h.z, a2);
            a3 = fmaf(h3 ? w0 : w1, h.w, a3);
        }
    }
#pragma unroll
    for (int off = LPE; off < 64; off <<= 1) {
        a0 += __shfl_xor(a0, off);
        a1 += __shfl_xor(a1, off);
        a2 += __shfl_xor(a2, off);
        a3 += __shfl_xor(a3, off);
    }
    if (g == 0 && chA) {
        float bx = (ch4 + 0 < HC) ? bias[ch4 + 0] : 0.f;
        float by = (ch4 + 1 < HC) ? bias[ch4 + 1] : 0.f;
        float bz = (ch4 + 2 < HC) ? bias[ch4 + 2] : 0.f;
        float bw = (ch4 + 3 < HC) ? bias[ch4 + 3] : 0.f;
        float v0 = fmaxf(a0 + bx, 0.f);
        float v1 = fmaxf(a1 + by, 0.f);
        float v2 = fmaxf(a2 + bz, 0.f);
        float v3 = fmaxf(a3 + bw, 0.f);
        ushort4 h, lo;
        h.x = f2bf(v0); lo.x = f2bf(v0 - bf2f(h.x));
        h.y = f2bf(v1); lo.y = f2bf(v1 - bf2f(h.y));
        h.z = f2bf(v2); lo.z = f2bf(v2 - bf2f(h.z));
        h.w = f2bf(v3); lo.w = f2bf(v3 - bf2f(h.w));
        *(ushort4*)(outHi + (size_t)i * ldo + ch4) = h;
        *(ushort4*)(outLo + (size_t)i * ldo + ch4) = lo;
    }
    for (int z = HCpad + lane * 4; z < ldo; z += 256) {
        ushort4 zz; zz.x = zz.y = zz.z = zz.w = 0;
        *(ushort4*)(outHi + (size_t)i * ldo + z) = zz;
        *(ushort4*)(outLo + (size_t)i * ldo + z) = zz;
    }
}

// ---------------- CSR build (with self-loops folded in) ----------------
__global__ void hist_self_k(const int* __restrict__ dst, int E,
                            int* __restrict__ counts, int n)
{
    int gid = blockIdx.x * blockDim.x + threadIdx.x;
    if (gid < E) atomicAdd(&counts[dst[gid]], 1);
    else if (gid < E + n) atomicAdd(&counts[gid - E], 1);
}

__global__ void scan_block_k(const int* __restrict__ in, int* __restrict__ out,
                             int* __restrict__ bsum, int n)
{
    __shared__ int sh[256];
    int gid = blockIdx.x * 256 + threadIdx.x;
    int v = (gid < n) ? in[gid] : 0;
    sh[threadIdx.x] = v;
    __syncthreads();
    for (int off = 1; off < 256; off <<= 1) {
        int t = (threadIdx.x >= off) ? sh[threadIdx.x - off] : 0;
        __syncthreads();
        sh[threadIdx.x] += t;
        __syncthreads();
    }
    int incl = sh[threadIdx.x];
    if (gid < n) out[gid] = incl - v;
    if (threadIdx.x == 255) bsum[blockIdx.x] = incl;
}

__global__ void scan_tops_k(const int* __restrict__ bsum, int* __restrict__ boff)
{
    __shared__ int sh[256];
    int v = bsum[threadIdx.x];
    sh[threadIdx.x] = v;
    __syncthreads();
    for (int off = 1; off < 256; off <<= 1) {
        int t = (threadIdx.x >= off) ? sh[threadIdx.x - off] : 0;
        __syncthreads();
        sh[threadIdx.x] += t;
        __syncthreads();
    }
    boff[threadIdx.x] = sh[threadIdx.x] - v;
}

__global__ void scan_add_k(int* __restrict__ indptr, const int* __restrict__ boff,
                           int n, int Etot)
{
    int gid = blockIdx.x * 256 + threadIdx.x;
    if (gid < n) indptr[gid] += boff[blockIdx.x];
    if (gid == 0) indptr[n] = Etot;
}

__global__ void fill_all_k(const int* __restrict__ src, const int* __restrict__ dst,
                           int E, const int* __restrict__ indptr,
                           int* __restrict__ cursor, int* __restrict__ csr_src, int n)
{
    int gid = blockIdx.x * blockDim.x + threadIdx.x;
    if (gid < E) {
        int d = dst[gid];
        int pos = atomicAdd(&cursor[d], 1);
        csr_src[indptr[d] + pos] = src[gid];
    } else if (gid < E + n) {
        int i = gid - E;
        int pos = atomicAdd(&cursor[i], 1);
        csr_src[indptr[i] + pos] = i;
    }
}

// ---------------- launch ----------------
extern "C" void kernel_launch(void* const* d_in, const int* in_sizes, int n_in,
                              void* d_out, int out_size, void* d_ws, size_t ws_size,
                              hipStream_t stream)
{
    (void)in_sizes; (void)n_in; (void)out_size; (void)ws_size;
    const int N = N_NODES;
    const int E = N_EDGES;
    const int Etot = E + N;

    const float* x = (const float*)d_in[0];
    const int* ei = (const int*)d_in[1];
    const float* Wc[4] = {(const float*)d_in[3], (const float*)d_in[7],
                          (const float*)d_in[11], (const float*)d_in[15]};
    const float* AS[4] = {(const float*)d_in[4], (const float*)d_in[8],
                          (const float*)d_in[12], (const float*)d_in[16]};
    const float* AD[4] = {(const float*)d_in[5], (const float*)d_in[9],
                          (const float*)d_in[13], (const float*)d_in[17]};
    const float* Bc[4] = {(const float*)d_in[6], (const float*)d_in[10],
                          (const float*)d_in[14], (const float*)d_in[18]};
    const float* LW[4] = {(const float*)d_in[19], (const float*)d_in[21],
                          (const float*)d_in[23], (const float*)d_in[25]};
    const float* LB[4] = {(const float*)d_in[20], (const float*)d_in[22],
                          (const float*)d_in[24], (const float*)d_in[26]};

    char* w = (char*)d_ws;
    auto alloc = [&](size_t bytes) -> char* {
        char* p = w; w += (bytes + 255) & ~(size_t)255; return p;
    };
    float* bufC = (float*)alloc((size_t)N * 252 * 4);            // GEMM out, fp32
    unsigned short* actHi = (unsigned short*)alloc((size_t)N * 256 * 2);
    unsigned short* actLo = (unsigned short*)alloc((size_t)N * 256 * 2);
    float4* meta = (float4*)alloc((size_t)Etot * 16);
    // MLP intermediates
    unsigned short* mlp1Hi = (unsigned short*)alloc((size_t)8192 * 224 * 2);
    unsigned short* mlp1Lo = (unsigned short*)alloc((size_t)8192 * 224 * 2);
    unsigned short* mlp2Hi = (unsigned short*)alloc((size_t)8192 * 128 * 2);
    unsigned short* mlp2Lo = (unsigned short*)alloc((size_t)8192 * 128 * 2);
    unsigned short* mlp3Hi = (unsigned short*)alloc((size_t)8192 * 128 * 2);
    unsigned short* mlp3Lo = (unsigned short*)alloc((size_t)8192 * 128 * 2);
    int* csr    = (int*)alloc((size_t)Etot * 4);
    // alSD (4 layers x [alS|alD]) + counts/cursor: contiguous, single memset
    float* alSD = (float*)alloc((size_t)N * 4 * 4 * 4 + (size_t)N * 2 * 4);
    int* cnt2   = (int*)(alSD + (size_t)N * 16);
    int* counts = cnt2;
    int* cursor = cnt2 + N;
    int* indptr = (int*)alloc((size_t)(N + 8) * 4);
    int* bsum   = (int*)alloc(1024);
    int* boff   = (int*)alloc(1024);

    const int KpConv[4] = {352, 256, 160, 128};
    const int NpConv[4] = {256, 192, 128, 64};
    const int KpLin[4]  = {512, 224, 128, 128};
    const int NpLin[4]  = {256, 128, 128, 64};
    unsigned short *WtHi[4], *WtLo[4], *LtHi[4], *LtLo[4];
    for (int l = 0; l < 4; ++l) {
        WtHi[l] = (unsigned short*)alloc((size_t)NpConv[l] * KpConv[l] * 2);
        WtLo[l] = (unsigned short*)alloc((size_t)NpConv[l] * KpConv[l] * 2);
    }
    for (int l = 0; l < 4; ++l) {
        LtHi[l] = (unsigned short*)alloc((size_t)NpLin[l] * KpLin[l] * 2);
        LtLo[l] = (unsigned short*)alloc((size_t)NpLin[l] * KpLin[l] * 2);
    }

    const int* esrc = ei;
    const int* edst = ei + E;

    // ---- CSR by dst incl. self-loops; zero al buffers + counts in one memset ----
    hipMemsetAsync(alSD, 0, (size_t)N * 4 * 4 * 4 + (size_t)N * 2 * 4, stream);
    hist_self_k<<<(E + N) / 256, 256, 0, stream>>>(edst, E, counts, N);
    scan_block_k<<<N / 256, 256, 0, stream>>>(counts, indptr, bsum, N);
    scan_tops_k<<<1, 256, 0, stream>>>(bsum, boff);
    scan_add_k<<<N / 256, 256, 0, stream>>>(indptr, boff, N, Etot);
    fill_all_k<<<(E + N) / 256, 256, 0, stream>>>(esrc, edst, E, indptr, cursor, csr, N);

    // ---- weight decompose (one kernel for all 8) ----
    const int Kc[4] = {336, 250, 150, 100}, Nc[4] = {250, 150, 100, 60};
    const int Kl[4] = {480, 200, 100, 100}, Nl[4] = {200, 100, 100, 29};
    WtJobs jobs;
    int nb = 0;
    for (int l = 0; l < 4; ++l) {
        jobs.j[l] = {Wc[l], WtHi[l], WtLo[l], Kc[l], Nc[l], KpConv[l], 0, nb};
        nb += NpConv[l];
    }
    for (int l = 0; l < 4; ++l) {
        jobs.j[4 + l] = {LW[l], LtHi[l], LtLo[l], Kl[l], Nl[l], KpLin[l],
                         l == 0 ? 1 : 0, nb};
        nb += NpLin[l];
    }
    wt_decomp_all<<<nb, 256, 0, stream>>>(jobs);

    // ---- 4 GAT layers ----
    const int HCp[4]  = {252, 152, 100, 60};   // fp32 GEMM-out leading dim
    const int ldoA[4] = {256, 160, 128, 64};   // bf16 act leading dim (= next Kp)
    const int ldaA[4] = {336, 256, 160, 128};  // A leading dim into GEMM
    for (int l = 0; l < 4; ++l) {
        int C = Nc[l] / 2, HC = Nc[l];
        float* alS = alSD + (size_t)l * N * 4;
        float* alD = alS + (size_t)N * 2;
        if (l == 0) {
            gemm_mfma<128><<<dim3(2, N / 128), 256, 0, stream>>>(
                x, 336, nullptr, nullptr, 336, 352,
                WtHi[0], WtLo[0], nullptr, 0,
                bufC, nullptr, nullptr, HCp[0], HCp[0], 0,
                AS[0], AD[0], alS, alD, C, HC);
        } else if (l == 1) {
            gemm_mfma<64><<<dim3(3, N / 128), 256, 0, stream>>>(
                nullptr, 0, actHi, actLo, ldaA[1], KpConv[1],
                WtHi[1], WtLo[1], nullptr, 0,
                bufC, nullptr, nullptr, HCp[1], HCp[1], 0,
                AS[1], AD[1], alS, alD, C, HC);
        } else if (l == 2) {
            gemm_mfma<128><<<dim3(1, N / 128), 256, 0, stream>>>(
                nullptr, 0, actHi, actLo, ldaA[2], KpConv[2],
                WtHi[2], WtLo[2], nullptr, 0,
                bufC, nullptr, nullptr, HCp[2], HCp[2], 0,
                AS[2], AD[2], alS, alD, C, HC);
        } else {
            gemm_mfma<64><<<dim3(1, N / 128), 256, 0, stream>>>(
                nullptr, 0, actHi, actLo, ldaA[3], KpConv[3],
                WtHi[3], WtLo[3], nullptr, 0,
                bufC, nullptr, nullptr, HCp[3], HCp[3], 0,
                AS[3], AD[3], alS, alD, C, HC);
        }
        if (l == 0) {
            attn_meta<<<N / 4, 256, 0, stream>>>(alS, alD, indptr, csr, meta, N);
            gat_gather<32, 2><<<N * 2 / 4, 256, 0, stream>>>(
                bufC, meta, indptr, Bc[0],
                actHi, actLo, ldoA[0], N, C, HC, HCp[0]);
        } else if (l == 1) {
            attn_meta<<<N / 4, 256, 0, stream>>>(alS, alD, indptr, csr, meta, N);
            gat_gather<32, 2><<<N * 2 / 4, 256, 0, stream>>>(
                bufC, meta, indptr, Bc[1],
                actHi, actLo, ldoA[1], N, C, HC, HCp[1]);
        } else if (l == 2) {
            gat_gather_fused<32><<<N / 4, 256, 0, stream>>>(
                bufC, alS, alD, indptr, csr, Bc[2],
                actHi, actLo, ldoA[2], N, C, HC, HCp[2]);
        } else {
            gat_gather_fused<16><<<N / 4, 256, 0, stream>>>(
                bufC, alS, alD, indptr, csr, Bc[3],
                actHi, actLo, ldoA[3], N, C, HC, HCp[3]);
        }
    }

    // ---- MLP head: [8192,480(512 remapped)] -> 200 -> 100 -> 100 -> 29 ----
    gemm_mfma<128><<<dim3(2, 64), 256, 0, stream>>>(
        nullptr, 0, actHi, actLo, 512, 512,
        LtHi[0], LtLo[0], LB[0], 200,
        nullptr, mlp1Hi, mlp1Lo, 224, 224, 1,
        nullptr, nullptr, nullptr, nullptr, 0, 0);
    gemm_mfma<128><<<dim3(1, 64), 256, 0, stream>>>(
        nullptr, 0, mlp1Hi, mlp1Lo, 224, 224,
        LtHi[1], LtLo[1], LB[1], 100,
        nullptr, mlp2Hi, mlp2Lo, 128, 128, 1,
        nullptr, nullptr, nullptr, nullptr, 0, 0);
    gemm_mfma<128><<<dim3(1, 64), 256, 0, stream>>>(
        nullptr, 0, mlp2Hi, mlp2Lo, 128, 128,
        LtHi[2], LtLo[2], LB[2], 100,
        nullptr, mlp3Hi, mlp3Lo, 128, 128, 1,
        nullptr, nullptr, nullptr, nullptr, 0, 0);
    gemm_mfma<64><<<dim3(1, 64), 256, 0, stream>>>(
        nullptr, 0, mlp3Hi, mlp3Lo, 128, 128,
        LtHi[3], LtLo[3], LB[3], 29,
        (float*)d_out, nullptr, nullptr, 29, 29, 0,
        nullptr, nullptr, nullptr, nullptr, 0, 0);
}

// Round 10
// 1017.111 us; speedup vs baseline: 1.0693x; 1.0220x over previous
//
#include <hip/hip_runtime.h>
#include <hip/hip_bf16.h>
#include <stdint.h>

#define N_NODES 65536
#define N_EDGES (N_NODES * 16)
#define NEG_SLOPE 0.2f

typedef short bf16x8 __attribute__((ext_vector_type(8)));   // 8 bf16 in 4 VGPRs
typedef float f32x4 __attribute__((ext_vector_type(4)));

__device__ __forceinline__ unsigned short f2bf(float f) {
    unsigned u = __float_as_uint(f);
    u += 0x7fffu + ((u >> 16) & 1u);       // RNE
    return (unsigned short)(u >> 16);
}
__device__ __forceinline__ float bf2f(unsigned short h) {
    return __uint_as_float(((unsigned)h) << 16);
}
__device__ __forceinline__ void load_lds16(const void* g, void* l) {
    __builtin_amdgcn_global_load_lds(
        (const __attribute__((address_space(1))) unsigned int*)g,
        (__attribute__((address_space(3))) unsigned int*)l, 16, 0, 0);
}

// ---------------- MFMA GEMM: C[M,Nw] = A[M,Kp] @ Wt^T (+bias,+relu) ----------------
// A: fp32 (A32 path, converted during staging) or bf16 hi/lo pair.
// Wt transposed [n][Kp] bf16 hi/lo, zero-padded.
// Split-bf16: acc += Ahi*Bhi + Alo*Bhi + Ahi*Blo  (fp32 MFMA accumulate).
// Block 256 = 4 waves; tile 128(M) x TN(N), TN in {64,128}; BK=32.
// If asrc != null: also computes per-row attention dots al_s/al_d (atomicAdd).
template<int TN>
__global__ __launch_bounds__(256) void gemm_mfma(
    const float* __restrict__ A32, int KA,
    const unsigned short* __restrict__ Ahi, const unsigned short* __restrict__ Alo,
    int lda, int Kp,
    const unsigned short* __restrict__ Bhi, const unsigned short* __restrict__ Blo,
    const float* __restrict__ bias, int Nbias,
    float* __restrict__ C32,
    unsigned short* __restrict__ Chi, unsigned short* __restrict__ Clo,
    int ldc, int Nw, int relu,
    const float* __restrict__ asrc, const float* __restrict__ adst,
    float* __restrict__ alS, float* __restrict__ alD, int Cal, int HCal)
{
    constexpr int NI = TN / 32;                 // N-frags per wave
    __shared__ unsigned short sAhi[128 * 32], sAlo[128 * 32];
    __shared__ unsigned short sBhi[TN * 32],  sBlo[TN * 32];
    __shared__ float sAl[128][2][4];
    const int tid = threadIdx.x;
    const int wave = tid >> 6, lane = tid & 63;
    const int row0 = blockIdx.y * 128;
    const int col0 = blockIdx.x * TN;
    const int wm = (wave & 1) * 64, wn = (wave >> 1) * (TN / 2);
    const int mlane = lane & 15, q = lane >> 4;

    f32x4 acc[4][NI];
#pragma unroll
    for (int a = 0; a < 4; ++a)
#pragma unroll
        for (int b = 0; b < NI; ++b) acc[a][b] = (f32x4){0.f, 0.f, 0.f, 0.f};

    for (int k0 = 0; k0 < Kp; k0 += 32) {
        __syncthreads();
        if (A32) {
            // fp32 -> bf16 hi/lo conversion staging (layer 1 only)
            const int r = tid >> 1, cbase = (tid & 1) * 16;
            const float* Ap = A32 + (size_t)(row0 + r) * lda;
#pragma unroll
            for (int j = 0; j < 4; ++j) {
                int kc = k0 + cbase + j * 4;
                float4 v = make_float4(0.f, 0.f, 0.f, 0.f);
                if (kc < KA) v = *(const float4*)(Ap + kc);
                ushort4 h, l;
                h.x = f2bf(v.x); l.x = f2bf(v.x - bf2f(h.x));
                h.y = f2bf(v.y); l.y = f2bf(v.y - bf2f(h.y));
                h.z = f2bf(v.z); l.z = f2bf(v.z - bf2f(h.z));
                h.w = f2bf(v.w); l.w = f2bf(v.w - bf2f(h.w));
                *(ushort4*)(sAhi + r * 32 + cbase + j * 4) = h;
                *(ushort4*)(sAlo + r * 32 + cbase + j * 4) = l;
            }
        } else {
            // async global->LDS, 16B/lane; LDS dst = wave-uniform base + lane*16
#pragma unroll
            for (int cc = 0; cc < 2; ++cc) {
                int c = wave * 2 + cc;                 // 8 chunks of 16 rows
                int r = c * 16 + (lane >> 2);
                size_t goff = (size_t)(row0 + r) * lda + k0 + (lane & 3) * 8;
                load_lds16(Ahi + goff, sAhi + c * 512);
                load_lds16(Alo + goff, sAlo + c * 512);
            }
        }
        {
#pragma unroll
            for (int cc = 0; cc < TN / 64; ++cc) {
                int c = wave * (TN / 64) + cc;         // TN/16 chunks of 16 rows
                int r = c * 16 + (lane >> 2);
                size_t goff = (size_t)(col0 + r) * Kp + k0 + (lane & 3) * 8;
                load_lds16(Bhi + goff, sBhi + c * 512);
                load_lds16(Blo + goff, sBlo + c * 512);
            }
        }
        __syncthreads();

        bf16x8 ah[4], al[4], bh[NI], bl[NI];
#pragma unroll
        for (int mi = 0; mi < 4; ++mi) {
            int m = wm + mi * 16 + mlane;
            ah[mi] = *(const bf16x8*)(sAhi + m * 32 + q * 8);
            al[mi] = *(const bf16x8*)(sAlo + m * 32 + q * 8);
        }
#pragma unroll
        for (int ni = 0; ni < NI; ++ni) {
            int n = wn + ni * 16 + mlane;
            bh[ni] = *(const bf16x8*)(sBhi + n * 32 + q * 8);
            bl[ni] = *(const bf16x8*)(sBlo + n * 32 + q * 8);
        }
#pragma unroll
        for (int mi = 0; mi < 4; ++mi)
#pragma unroll
            for (int ni = 0; ni < NI; ++ni) {
                acc[mi][ni] = __builtin_amdgcn_mfma_f32_16x16x32_bf16(ah[mi], bh[ni], acc[mi][ni], 0, 0, 0);
                acc[mi][ni] = __builtin_amdgcn_mfma_f32_16x16x32_bf16(al[mi], bh[ni], acc[mi][ni], 0, 0, 0);
                acc[mi][ni] = __builtin_amdgcn_mfma_f32_16x16x32_bf16(ah[mi], bl[ni], acc[mi][ni], 0, 0, 0);
            }
    }

    // epilogue: C/D frag layout col=lane&15, row=(lane>>4)*4+reg
#pragma unroll
    for (int ni = 0; ni < NI; ++ni) {
        int col = col0 + wn + ni * 16 + mlane;
        if (col >= Nw) continue;
        float bv = (bias && col < Nbias) ? bias[col] : 0.f;
#pragma unroll
        for (int mi = 0; mi < 4; ++mi) {
#pragma unroll
            for (int reg = 0; reg < 4; ++reg) {
                int row = row0 + wm + mi * 16 + q * 4 + reg;
                float v = acc[mi][ni][reg] + bv;
                if (relu) v = fmaxf(v, 0.f);
                size_t off = (size_t)row * ldc + col;
                if (Chi) {
                    unsigned short h = f2bf(v);
                    Chi[off] = h;
                    Clo[off] = f2bf(v - bf2f(h));
                } else {
                    C32[off] = v;
                }
            }
        }
    }

    // fused attention-logit dots: al_s[row,h] += sum_c h[row,c]*a_s[h,c], same for a_d
    if (asrc) {
        float asv[NI], adv[NI];
        bool head0[NI];
#pragma unroll
        for (int ni = 0; ni < NI; ++ni) {
            int col = col0 + wn + ni * 16 + mlane;
            bool valid = col < HCal;
            head0[ni] = col < Cal;
            asv[ni] = valid ? asrc[col] : 0.f;
            adv[ni] = valid ? adst[col] : 0.f;
        }
#pragma unroll
        for (int mi = 0; mi < 4; ++mi) {
#pragma unroll
            for (int reg = 0; reg < 4; ++reg) {
                float s0 = 0.f, s1 = 0.f, d0 = 0.f, d1 = 0.f;
#pragma unroll
                for (int ni = 0; ni < NI; ++ni) {
                    float v = acc[mi][ni][reg];
                    if (head0[ni]) { s0 += v * asv[ni]; d0 += v * adv[ni]; }
                    else           { s1 += v * asv[ni]; d1 += v * adv[ni]; }
                }
#pragma unroll
                for (int off = 1; off < 16; off <<= 1) {
                    s0 += __shfl_xor(s0, off); s1 += __shfl_xor(s1, off);
                    d0 += __shfl_xor(d0, off); d1 += __shfl_xor(d1, off);
                }
                if (mlane == 0) {
                    int rl = wm + mi * 16 + q * 4 + reg;
                    int slot = wave >> 1;
                    sAl[rl][slot][0] = s0; sAl[rl][slot][1] = s1;
                    sAl[rl][slot][2] = d0; sAl[rl][slot][3] = d1;
                }
            }
        }
        __syncthreads();
        if (tid < 128) {
            int row = row0 + tid;
            float v0 = sAl[tid][0][0] + sAl[tid][1][0];
            float v1 = sAl[tid][0][1] + sAl[tid][1][1];
            float v2 = sAl[tid][0][2] + sAl[tid][1][2];
            float v3 = sAl[tid][0][3] + sAl[tid][1][3];
            atomicAdd(&alS[row * 2 + 0], v0);
            atomicAdd(&alS[row * 2 + 1], v1);
            atomicAdd(&alD[row * 2 + 0], v2);
            atomicAdd(&alD[row * 2 + 1], v3);
        }
    }
}

// ------------- fused MLP head: 4 layers in one kernel, 32 rows/block -------------
// Block owns rows [row0, row0+32); intermediates live in LDS (hi/lo bf16, same
// rounding as the unfused path -> bitwise-identical output). Weights stream from
// global per k-tile. Wave tiling: wm=(wave&1)*16 rows, wn=(wave>>1)*(NI*16) cols.
template<int NI>
__device__ __forceinline__ void mlp_layer(
    const unsigned short* aHi, const unsigned short* aLo, int ldaS, int K,
    const unsigned short* __restrict__ Bhi, const unsigned short* __restrict__ Blo,
    int Kp,
    unsigned short* sBh, unsigned short* sBl,
    const float* __restrict__ bias, int Nbias, int colBase,
    unsigned short* oHi, unsigned short* oLo, int ldo, int Nstore,
    float* __restrict__ gOut, int row0, int relu,
    int wave, int lane)
{
    const int mlane = lane & 15, q = lane >> 4;
    const int wm = (wave & 1) * 16;
    const int wn = (wave >> 1) * (NI * 16);
    f32x4 acc[NI];
#pragma unroll
    for (int b = 0; b < NI; ++b) acc[b] = (f32x4){0.f, 0.f, 0.f, 0.f};

    for (int k0 = 0; k0 < K; k0 += 32) {
        __syncthreads();
        for (int c = wave; c < NI * 2; c += 4) {   // stage B rows (N = NI*32)
            int r = c * 16 + (lane >> 2);
            size_t goff = (size_t)r * Kp + k0 + (lane & 3) * 8;
            load_lds16(Bhi + goff, sBh + c * 512);
            load_lds16(Blo + goff, sBl + c * 512);
        }
        __syncthreads();

        bf16x8 ah, al, bh[NI], bl[NI];
        ah = *(const bf16x8*)(aHi + (wm + mlane) * ldaS + k0 + q * 8);
        al = *(const bf16x8*)(aLo + (wm + mlane) * ldaS + k0 + q * 8);
#pragma unroll
        for (int ni = 0; ni < NI; ++ni) {
            int n = wn + ni * 16 + mlane;
            bh[ni] = *(const bf16x8*)(sBh + n * 32 + q * 8);
            bl[ni] = *(const bf16x8*)(sBl + n * 32 + q * 8);
        }
#pragma unroll
        for (int ni = 0; ni < NI; ++ni) {
            acc[ni] = __builtin_amdgcn_mfma_f32_16x16x32_bf16(ah, bh[ni], acc[ni], 0, 0, 0);
            acc[ni] = __builtin_amdgcn_mfma_f32_16x16x32_bf16(al, bh[ni], acc[ni], 0, 0, 0);
            acc[ni] = __builtin_amdgcn_mfma_f32_16x16x32_bf16(ah, bl[ni], acc[ni], 0, 0, 0);
        }
    }
    __syncthreads();   // all reads of aHi/aLo done before caller overwrites

#pragma unroll
    for (int ni = 0; ni < NI; ++ni) {
        int colg = colBase + wn + ni * 16 + mlane;
        float bv = (colg < Nbias) ? bias[colg] : 0.f;
#pragma unroll
        for (int reg = 0; reg < 4; ++reg) {
            int row = wm + q * 4 + reg;
            float v = acc[ni][reg] + bv;
            if (relu) v = fmaxf(v, 0.f);
            if (gOut) {
                if (colg < 29) gOut[(size_t)(row0 + row) * 29 + colg] = v;
            } else if (colg < Nstore) {
                unsigned short h = f2bf(v);
                oHi[row * ldo + colg] = h;
                oLo[row * ldo + colg] = f2bf(v - bf2f(h));
            }
        }
    }
}

__global__ __launch_bounds__(256) void mlp_fused(
    const unsigned short* __restrict__ actHi, const unsigned short* __restrict__ actLo,
    const unsigned short* __restrict__ L1h, const unsigned short* __restrict__ L1l,
    const unsigned short* __restrict__ L2h, const unsigned short* __restrict__ L2l,
    const unsigned short* __restrict__ L3h, const unsigned short* __restrict__ L3l,
    const unsigned short* __restrict__ L4h, const unsigned short* __restrict__ L4l,
    const float* __restrict__ B1, const float* __restrict__ B2,
    const float* __restrict__ B3, const float* __restrict__ B4,
    float* __restrict__ out)
{
    __shared__ unsigned short b1h[32 * 224], b1l[32 * 224];   // L1 out / L3 out
    __shared__ unsigned short b2h[32 * 128], b2l[32 * 128];   // L2 out
    __shared__ unsigned short sAh[32 * 32],  sAl[32 * 32];    // L1 A staging
    __shared__ unsigned short sBh[128 * 32], sBl[128 * 32];   // B staging
    const int tid = threadIdx.x;
    const int wave = tid >> 6, lane = tid & 63;
    const int row0 = blockIdx.x * 32;
    const int mlane = lane & 15, q = lane >> 4;
    const int wm = (wave & 1) * 16;
    const int wn = (wave >> 1) * 64;

    // ---- layer 1: [32,512] @ L1^T -> b1 [32,224], two 128-col tiles ----
    for (int nt = 0; nt < 2; ++nt) {
        const unsigned short* Bh = L1h + (size_t)nt * 128 * 512;
        const unsigned short* Bl = L1l + (size_t)nt * 128 * 512;
        f32x4 acc[4];
#pragma unroll
        for (int b = 0; b < 4; ++b) acc[b] = (f32x4){0.f, 0.f, 0.f, 0.f};
        for (int k0 = 0; k0 < 512; k0 += 32) {
            __syncthreads();
            for (int c = wave; c < 2; c += 4) {      // A: 32 rows
                int r = c * 16 + (lane >> 2);
                size_t goff = (size_t)(row0 + r) * 512 + k0 + (lane & 3) * 8;
                load_lds16(actHi + goff, sAh + c * 512);
                load_lds16(actLo + goff, sAl + c * 512);
            }
            for (int c = wave; c < 8; c += 4) {      // B: 128 rows
                int r = c * 16 + (lane >> 2);
                size_t goff = (size_t)r * 512 + k0 + (lane & 3) * 8;
                load_lds16(Bh + goff, sBh + c * 512);
                load_lds16(Bl + goff, sBl + c * 512);
            }
            __syncthreads();
            bf16x8 ah = *(const bf16x8*)(sAh + (wm + mlane) * 32 + q * 8);
            bf16x8 al = *(const bf16x8*)(sAl + (wm + mlane) * 32 + q * 8);
#pragma unroll
            for (int ni = 0; ni < 4; ++ni) {
                int n = wn + ni * 16 + mlane;
                bf16x8 bh = *(const bf16x8*)(sBh + n * 32 + q * 8);
                bf16x8 bl = *(const bf16x8*)(sBl + n * 32 + q * 8);
                acc[ni] = __builtin_amdgcn_mfma_f32_16x16x32_bf16(ah, bh, acc[ni], 0, 0, 0);
                acc[ni] = __builtin_amdgcn_mfma_f32_16x16x32_bf16(al, bh, acc[ni], 0, 0, 0);
                acc[ni] = __builtin_amdgcn_mfma_f32_16x16x32_bf16(ah, bl, acc[ni], 0, 0, 0);
            }
        }
        __syncthreads();
#pragma unroll
        for (int ni = 0; ni < 4; ++ni) {
            int colg = nt * 128 + wn + ni * 16 + mlane;
            float bv = (colg < 200) ? B1[colg] : 0.f;
#pragma unroll
            for (int reg = 0; reg < 4; ++reg) {
                int row = wm + q * 4 + reg;
                float v = fmaxf(acc[ni][reg] + bv, 0.f);
                if (colg < 224) {
                    unsigned short h = f2bf(v);
                    b1h[row * 224 + colg] = h;
                    b1l[row * 224 + colg] = f2bf(v - bf2f(h));
                }
            }
        }
    }
    __syncthreads();

    // ---- layer 2: b1[32,224] -> b2[32,128] ----
    mlp_layer<4>(b1h, b1l, 224, 224, L2h, L2l, 224, sBh, sBl,
                 B2, 100, 0, b2h, b2l, 128, 128, nullptr, 0, 1, wave, lane);
    __syncthreads();
    // ---- layer 3: b2[32,128] -> b1[32,128] (reuse, ld 128) ----
    mlp_layer<4>(b2h, b2l, 128, 128, L3h, L3l, 128, sBh, sBl,
                 B3, 100, 0, b1h, b1l, 128, 128, nullptr, 0, 1, wave, lane);
    __syncthreads();
    // ---- layer 4: b1[32,128] -> out[32,29] fp32 ----
    mlp_layer<2>(b1h, b1l, 128, 128, L4h, L4l, 128, sBh, sBl,
                 B4, 29, 0, nullptr, nullptr, 0, 0, out, row0, 0, wave, lane);
}

// ---------------- weight transpose + bf16 hi/lo decompose (all 8 in one) ----------
struct WtJob {
    const float* W; unsigned short* Whi; unsigned short* Wlo;
    int K, N, Kp, remap, nb0;
};
struct WtJobs { WtJob j[8]; };

__global__ void wt_decomp_all(WtJobs jobs)
{
    int b = blockIdx.x;
    int idx = 0;
#pragma unroll
    for (int i = 1; i < 8; ++i)
        if (b >= jobs.j[i].nb0) idx = i;
    WtJob jb = jobs.j[idx];
    int n = b - jb.nb0;
    for (int k = threadIdx.x; k < jb.Kp; k += 256) {
        int ks = k, valid = 1;
        if (jb.remap) {
            int bb = k >> 6, r = k & 63;
            if (r < 60) ks = bb * 60 + r; else valid = 0;
        }
        float v = 0.f;
        if (valid && ks < jb.K && n < jb.N) v = jb.W[(size_t)ks * jb.N + n];
        unsigned short h = f2bf(v);
        jb.Whi[(size_t)n * jb.Kp + k] = h;
        jb.Wlo[(size_t)n * jb.Kp + k] = f2bf(v - bf2f(h));
    }
}

// ---------------- softmax weights -> packed meta {src, w0, w1, 0} (L1/L2) ----------
__global__ __launch_bounds__(256) void attn_meta(
    const float* __restrict__ al_s, const float* __restrict__ al_d,
    const int* __restrict__ indptr, const int* __restrict__ csr_src,
    float4* __restrict__ meta, int Nn)
{
    int wave = threadIdx.x >> 6, lane = threadIdx.x & 63;
    int i = blockIdx.x * 4 + wave;
    if (i >= Nn) return;
    int start = indptr[i], end = indptr[i + 1];
    float ad0 = al_d[2 * i], ad1 = al_d[2 * i + 1];

    int j0 = start + lane;
    int sreg = 0;
    float e0r = 0.f, e1r = 0.f;
    float m0 = -1e30f, m1 = -1e30f, den0 = 0.f, den1 = 0.f;
    if (j0 < end) {
        sreg = csr_src[j0];
        float2 as = *(const float2*)(al_s + 2 * sreg);
        e0r = as.x + ad0; e0r = e0r > 0.f ? e0r : NEG_SLOPE * e0r;
        e1r = as.y + ad1; e1r = e1r > 0.f ? e1r : NEG_SLOPE * e1r;
        m0 = e0r; den0 = 1.f;
        m1 = e1r; den1 = 1.f;
    }
    for (int j = j0 + 64; j < end; j += 64) {
        int s = csr_src[j];
        float2 as = *(const float2*)(al_s + 2 * s);
        float e0 = as.x + ad0; e0 = e0 > 0.f ? e0 : NEG_SLOPE * e0;
        float e1 = as.y + ad1; e1 = e1 > 0.f ? e1 : NEG_SLOPE * e1;
        float n0 = fmaxf(m0, e0);
        den0 = den0 * __expf(m0 - n0) + __expf(e0 - n0);
        m0 = n0;
        float n1 = fmaxf(m1, e1);
        den1 = den1 * __expf(m1 - n1) + __expf(e1 - n1);
        m1 = n1;
    }
#pragma unroll
    for (int off = 32; off; off >>= 1) {
        float mo0 = __shfl_xor(m0, off), do0 = __shfl_xor(den0, off);
        float n0 = fmaxf(m0, mo0);
        den0 = den0 * __expf(m0 - n0) + do0 * __expf(mo0 - n0);
        m0 = n0;
        float mo1 = __shfl_xor(m1, off), do1 = __shfl_xor(den1, off);
        float n1 = fmaxf(m1, mo1);
        den1 = den1 * __expf(m1 - n1) + do1 * __expf(mo1 - n1);
        m1 = n1;
    }
    float inv0 = 1.f / den0, inv1 = 1.f / den1;
    if (j0 < end) {
        float4 md;
        md.x = __int_as_float(sreg);
        md.y = __expf(e0r - m0) * inv0;
        md.z = __expf(e1r - m1) * inv1;
        md.w = 0.f;
        meta[j0] = md;
    }
    for (int j = j0 + 64; j < end; j += 64) {
        int s = csr_src[j];
        float2 as = *(const float2*)(al_s + 2 * s);
        float e0 = as.x + ad0; e0 = e0 > 0.f ? e0 : NEG_SLOPE * e0;
        float e1 = as.y + ad1; e1 = e1 > 0.f ? e1 : NEG_SLOPE * e1;
        float4 md;
        md.x = __int_as_float(s);
        md.y = __expf(e0 - m0) * inv0;
        md.z = __expf(e1 - m1) * inv1;
        md.w = 0.f;
        meta[j] = md;
    }
}

// ------- gather (meta path, L1/L2): out[i]=sum_j w_j*h[src_j] -> bf16 hi/lo -------
template<int LPE, int NCH>
__global__ __launch_bounds__(256) void gat_gather(
    const float* __restrict__ hlin, const float4* __restrict__ meta,
    const int* __restrict__ indptr, const float* __restrict__ bias,
    unsigned short* __restrict__ outHi, unsigned short* __restrict__ outLo,
    int ldo, int Nn, int C, int HC, int HCpad)
{
    constexpr int G = 64 / LPE;
    const int wave = threadIdx.x >> 6, lane = threadIdx.x & 63;
    const int slot = blockIdx.x * 4 + wave;
    const int i = slot / NCH;
    const int chunk = slot % NCH;
    if (i >= Nn) return;
    const int l = lane % LPE;
    const int g = lane / LPE;
    const int ch4 = chunk * LPE * 4 + l * 4;
    const bool chA = ch4 < HCpad;
    const int start = indptr[i], end = indptr[i + 1];

    float a0 = 0.f, a1 = 0.f, a2 = 0.f, a3 = 0.f;
    const bool h0 = (ch4 + 0) < C, h1 = (ch4 + 1) < C,
               h2 = (ch4 + 2) < C, h3 = (ch4 + 3) < C;

    for (int jb = start; jb < end; jb += 4 * G) {
#pragma unroll
        for (int u = 0; u < 4; ++u) {
            int j = jb + u * G + g;
            int jj = j < end ? j : end - 1;   // end-1 >= start (self-loop)
            float4 md = meta[jj];
            int s = __float_as_int(md.x);
            float w0 = md.y, w1 = md.z;
            if (j >= end) { w0 = 0.f; w1 = 0.f; }
            const float* hr = hlin + (size_t)s * HCpad;
            float4 h = chA ? *(const float4*)(hr + ch4)
                           : make_float4(0.f, 0.f, 0.f, 0.f);
            a0 = fmaf(h0 ? w0 : w1, h.x, a0);
            a1 = fmaf(h1 ? w0 : w1, h.y, a1);
            a2 = fmaf(h2 ? w0 : w1, h.z, a2);
            a3 = fmaf(h3 ? w0 : w1, h.w, a3);
        }
    }
#pragma unroll
    for (int off = LPE; off < 64; off <<= 1) {
        a0 += __shfl_xor(a0, off);
        a1 += __shfl_xor(a1, off);
        a2 += __shfl_xor(a2, off);
        a3 += __shfl_xor(a3, off);
    }
    if (g == 0 && chA) {
        float bx = (ch4 + 0 < HC) ? bias[ch4 + 0] : 0.f;
        float by = (ch4 + 1 < HC) ? bias[ch4 + 1] : 0.f;
        float bz = (ch4 + 2 < HC) ? bias[ch4 + 2] : 0.f;
        float bw = (ch4 + 3 < HC) ? bias[ch4 + 3] : 0.f;
        float v0 = fmaxf(a0 + bx, 0.f);
        float v1 = fmaxf(a1 + by, 0.f);
        float v2 = fmaxf(a2 + bz, 0.f);
        float v3 = fmaxf(a3 + bw, 0.f);
        ushort4 h, lo;
        h.x = f2bf(v0); lo.x = f2bf(v0 - bf2f(h.x));
        h.y = f2bf(v1); lo.y = f2bf(v1 - bf2f(h.y));
        h.z = f2bf(v2); lo.z = f2bf(v2 - bf2f(h.z));
        h.w = f2bf(v3); lo.w = f2bf(v3 - bf2f(h.w));
        *(ushort4*)(outHi + (size_t)i * ldo + ch4) = h;
        *(ushort4*)(outLo + (size_t)i * ldo + ch4) = lo;
    }
    if (chunk == 0) {
        for (int z = HCpad + lane * 4; z < ldo; z += 256) {
            ushort4 zz; zz.x = zz.y = zz.z = zz.w = 0;
            *(ushort4*)(outHi + (size_t)i * ldo + z) = zz;
            *(ushort4*)(outLo + (size_t)i * ldo + z) = zz;
        }
    }
}

// ------- fused stats+gather (L3/L4, one wave per node): stats in-kernel -------
template<int LPE>
__global__ __launch_bounds__(256) void gat_gather_fused(
    const float* __restrict__ hlin,
    const float* __restrict__ al_s, const float* __restrict__ al_d,
    const int* __restrict__ indptr, const int* __restrict__ csr_src,
    const float* __restrict__ bias,
    unsigned short* __restrict__ outHi, unsigned short* __restrict__ outLo,
    int ldo, int Nn, int C, int HC, int HCpad)
{
    constexpr int G = 64 / LPE;
    const int wave = threadIdx.x >> 6, lane = threadIdx.x & 63;
    const int i = blockIdx.x * 4 + wave;
    if (i >= Nn) return;
    const int start = indptr[i], end = indptr[i + 1];
    const float ad0 = al_d[2 * i], ad1 = al_d[2 * i + 1];

    float m0 = -1e30f, m1 = -1e30f, den0 = 0.f, den1 = 0.f;
    for (int j = start + lane; j < end; j += 64) {
        int s = csr_src[j];
        float2 as = *(const float2*)(al_s + 2 * s);
        float e0 = as.x + ad0; e0 = e0 > 0.f ? e0 : NEG_SLOPE * e0;
        float e1 = as.y + ad1; e1 = e1 > 0.f ? e1 : NEG_SLOPE * e1;
        float n0 = fmaxf(m0, e0);
        den0 = den0 * __expf(m0 - n0) + __expf(e0 - n0);
        m0 = n0;
        float n1 = fmaxf(m1, e1);
        den1 = den1 * __expf(m1 - n1) + __expf(e1 - n1);
        m1 = n1;
    }
#pragma unroll
    for (int off = 32; off; off >>= 1) {
        float mo0 = __shfl_xor(m0, off), do0 = __shfl_xor(den0, off);
        float n0 = fmaxf(m0, mo0);
        den0 = den0 * __expf(m0 - n0) + do0 * __expf(mo0 - n0);
        m0 = n0;
        float mo1 = __shfl_xor(m1, off), do1 = __shfl_xor(den1, off);
        float n1 = fmaxf(m1, mo1);
        den1 = den1 * __expf(m1 - n1) + do1 * __expf(mo1 - n1);
        m1 = n1;
    }
    const float inv0 = 1.f / den0, inv1 = 1.f / den1;

    const int l = lane % LPE;
    const int g = lane / LPE;
    const int ch4 = l * 4;
    const bool chA = ch4 < HCpad;
    float a0 = 0.f, a1 = 0.f, a2 = 0.f, a3 = 0.f;
    const bool h0 = (ch4 + 0) < C, h1 = (ch4 + 1) < C,
               h2 = (ch4 + 2) < C, h3 = (ch4 + 3) < C;

    for (int jb = start; jb < end; jb += 4 * G) {
#pragma unroll
        for (int u = 0; u < 4; ++u) {
            int j = jb + u * G + g;
            int jj = j < end ? j : end - 1;   // end-1 >= start (self-loop)
            int s = csr_src[jj];
            float2 as = *(const float2*)(al_s + 2 * s);
            float e0 = as.x + ad0; e0 = e0 > 0.f ? e0 : NEG_SLOPE * e0;
            float e1 = as.y + ad1; e1 = e1 > 0.f ? e1 : NEG_SLOPE * e1;
            float w0 = __expf(e0 - m0) * inv0;
            float w1 = __expf(e1 - m1) * inv1;
            if (j >= end) { w0 = 0.f; w1 = 0.f; }
            const float* hr = hlin + (size_t)s * HCpad;
            float4 h = chA ? *(const float4*)(hr + ch4)
                           : make_float4(0.f, 0.f, 0.f, 0.f);
            a0 = fmaf(h0 ? w0 : w1, h.x, a0);
            a1 = fmaf(h1 ? w0 : w1, h.y, a1);
            a2 = fmaf(h2 ? w0 : w1, h.z, a2);
            a3 = fmaf(h3 ? w0 : w1, h.w, a3);
        }
    }
#pragma unroll
    for (int off = LPE; off < 64; off <<= 1) {
        a0 += __shfl_xor(a0, off);
        a1 += __shfl_xor(a1, off);
        a2 += __shfl_xor(a2, off);
        a3 += __shfl_xor(a3, off);
    }
    if (g == 0 && chA) {
        float bx = (ch4 + 0 < HC) ? bias[ch4 + 0] : 0.f;
        float by = (ch4 + 1 < HC) ? bias[ch4 + 1] : 0.f;
        float bz = (ch4 + 2 < HC) ? bias[ch4 + 2] : 0.f;
        float bw = (ch4 + 3 < HC) ? bias[ch4 + 3] : 0.f;
        float v0 = fmaxf(a0 + bx, 0.f);
        float v1 = fmaxf(a1 + by, 0.f);
        float v2 = fmaxf(a2 + bz, 0.f);
        float v3 = fmaxf(a3 + bw, 0.f);
        ushort4 h, lo;
        h.x = f2bf(v0); lo.x = f2bf(v0 - bf2f(h.x));
        h.y = f2bf(v1); lo.y = f2bf(v1 - bf2f(h.y));
        h.z = f2bf(v2); lo.z = f2bf(v2 - bf2f(h.z));
        h.w = f2bf(v3); lo.w = f2bf(v3 - bf2f(h.w));
        *(ushort4*)(outHi + (size_t)i * ldo + ch4) = h;
        *(ushort4*)(outLo + (size_t)i * ldo + ch4) = lo;
    }
    for (int z = HCpad + lane * 4; z < ldo; z += 256) {
        ushort4 zz; zz.x = zz.y = zz.z = zz.w = 0;
        *(ushort4*)(outHi + (size_t)i * ldo + z) = zz;
        *(ushort4*)(outLo + (size_t)i * ldo + z) = zz;
    }
}

// ---------------- CSR build (with self-loops folded in) ----------------
__global__ void hist_self_k(const int* __restrict__ dst, int E,
                            int* __restrict__ counts, int n)
{
    int gid = blockIdx.x * blockDim.x + threadIdx.x;
    if (gid < E) atomicAdd(&counts[dst[gid]], 1);
    else if (gid < E + n) atomicAdd(&counts[gid - E], 1);
}

__global__ void scan_block_k(const int* __restrict__ in, int* __restrict__ out,
                             int* __restrict__ bsum, int n)
{
    __shared__ int sh[256];
    int gid = blockIdx.x * 256 + threadIdx.x;
    int v = (gid < n) ? in[gid] : 0;
    sh[threadIdx.x] = v;
    __syncthreads();
    for (int off = 1; off < 256; off <<= 1) {
        int t = (threadIdx.x >= off) ? sh[threadIdx.x - off] : 0;
        __syncthreads();
        sh[threadIdx.x] += t;
        __syncthreads();
    }
    int incl = sh[threadIdx.x];
    if (gid < n) out[gid] = incl - v;
    if (threadIdx.x == 255) bsum[blockIdx.x] = incl;
}

__global__ void scan_tops_k(const int* __restrict__ bsum, int* __restrict__ boff)
{
    __shared__ int sh[256];
    int v = bsum[threadIdx.x];
    sh[threadIdx.x] = v;
    __syncthreads();
    for (int off = 1; off < 256; off <<= 1) {
        int t = (threadIdx.x >= off) ? sh[threadIdx.x - off] : 0;
        __syncthreads();
        sh[threadIdx.x] += t;
        __syncthreads();
    }
    boff[threadIdx.x] = sh[threadIdx.x] - v;
}

__global__ void scan_add_k(int* __restrict__ indptr, const int* __restrict__ boff,
                           int n, int Etot)
{
    int gid = blockIdx.x * 256 + threadIdx.x;
    if (gid < n) indptr[gid] += boff[blockIdx.x];
    if (gid == 0) indptr[n] = Etot;
}

__global__ void fill_all_k(const int* __restrict__ src, const int* __restrict__ dst,
                           int E, const int* __restrict__ indptr,
                           int* __restrict__ cursor, int* __restrict__ csr_src, int n)
{
    int gid = blockIdx.x * blockDim.x + threadIdx.x;
    if (gid < E) {
        int d = dst[gid];
        int pos = atomicAdd(&cursor[d], 1);
        csr_src[indptr[d] + pos] = src[gid];
    } else if (gid < E + n) {
        int i = gid - E;
        int pos = atomicAdd(&cursor[i], 1);
        csr_src[indptr[i] + pos] = i;
    }
}

// ---------------- launch ----------------
extern "C" void kernel_launch(void* const* d_in, const int* in_sizes, int n_in,
                              void* d_out, int out_size, void* d_ws, size_t ws_size,
                              hipStream_t stream)
{
    (void)in_sizes; (void)n_in; (void)out_size; (void)ws_size;
    const int N = N_NODES;
    const int E = N_EDGES;
    const int Etot = E + N;

    const float* x = (const float*)d_in[0];
    const int* ei = (const int*)d_in[1];
    const float* Wc[4] = {(const float*)d_in[3], (const float*)d_in[7],
                          (const float*)d_in[11], (const float*)d_in[15]};
    const float* AS[4] = {(const float*)d_in[4], (const float*)d_in[8],
                          (const float*)d_in[12], (const float*)d_in[16]};
    const float* AD[4] = {(const float*)d_in[5], (const float*)d_in[9],
                          (const float*)d_in[13], (const float*)d_in[17]};
    const float* Bc[4] = {(const float*)d_in[6], (const float*)d_in[10],
                          (const float*)d_in[14], (const float*)d_in[18]};
    const float* LW[4] = {(const float*)d_in[19], (const float*)d_in[21],
                          (const float*)d_in[23], (const float*)d_in[25]};
    const float* LB[4] = {(const float*)d_in[20], (const float*)d_in[22],
                          (const float*)d_in[24], (const float*)d_in[26]};

    char* w = (char*)d_ws;
    auto alloc = [&](size_t bytes) -> char* {
        char* p = w; w += (bytes + 255) & ~(size_t)255; return p;
    };
    float* bufC = (float*)alloc((size_t)N * 252 * 4);            // GEMM out, fp32
    unsigned short* actHi = (unsigned short*)alloc((size_t)N * 256 * 2);
    unsigned short* actLo = (unsigned short*)alloc((size_t)N * 256 * 2);
    float4* meta = (float4*)alloc((size_t)Etot * 16);
    int* csr    = (int*)alloc((size_t)Etot * 4);
    // alSD (4 layers x [alS|alD]) + counts/cursor: contiguous, single memset
    float* alSD = (float*)alloc((size_t)N * 4 * 4 * 4 + (size_t)N * 2 * 4);
    int* cnt2   = (int*)(alSD + (size_t)N * 16);
    int* counts = cnt2;
    int* cursor = cnt2 + N;
    int* indptr = (int*)alloc((size_t)(N + 8) * 4);
    int* bsum   = (int*)alloc(1024);
    int* boff   = (int*)alloc(1024);

    const int KpConv[4] = {352, 256, 160, 128};
    const int NpConv[4] = {256, 192, 128, 64};
    const int KpLin[4]  = {512, 224, 128, 128};
    const int NpLin[4]  = {256, 128, 128, 64};
    unsigned short *WtHi[4], *WtLo[4], *LtHi[4], *LtLo[4];
    for (int l = 0; l < 4; ++l) {
        WtHi[l] = (unsigned short*)alloc((size_t)NpConv[l] * KpConv[l] * 2);
        WtLo[l] = (unsigned short*)alloc((size_t)NpConv[l] * KpConv[l] * 2);
    }
    for (int l = 0; l < 4; ++l) {
        LtHi[l] = (unsigned short*)alloc((size_t)NpLin[l] * KpLin[l] * 2);
        LtLo[l] = (unsigned short*)alloc((size_t)NpLin[l] * KpLin[l] * 2);
    }

    const int* esrc = ei;
    const int* edst = ei + E;

    // ---- CSR by dst incl. self-loops; zero al buffers + counts in one memset ----
    hipMemsetAsync(alSD, 0, (size_t)N * 4 * 4 * 4 + (size_t)N * 2 * 4, stream);
    hist_self_k<<<(E + N) / 256, 256, 0, stream>>>(edst, E, counts, N);
    scan_block_k<<<N / 256, 256, 0, stream>>>(counts, indptr, bsum, N);
    scan_tops_k<<<1, 256, 0, stream>>>(bsum, boff);
    scan_add_k<<<N / 256, 256, 0, stream>>>(indptr, boff, N, Etot);
    fill_all_k<<<(E + N) / 256, 256, 0, stream>>>(esrc, edst, E, indptr, cursor, csr, N);

    // ---- weight decompose (one kernel for all 8) ----
    const int Kc[4] = {336, 250, 150, 100}, Nc[4] = {250, 150, 100, 60};
    const int Kl[4] = {480, 200, 100, 100}, Nl[4] = {200, 100, 100, 29};
    WtJobs jobs;
    int nb = 0;
    for (int l = 0; l < 4; ++l) {
        jobs.j[l] = {Wc[l], WtHi[l], WtLo[l], Kc[l], Nc[l], KpConv[l], 0, nb};
        nb += NpConv[l];
    }
    for (int l = 0; l < 4; ++l) {
        jobs.j[4 + l] = {LW[l], LtHi[l], LtLo[l], Kl[l], Nl[l], KpLin[l],
                         l == 0 ? 1 : 0, nb};
        nb += NpLin[l];
    }
    wt_decomp_all<<<nb, 256, 0, stream>>>(jobs);

    // ---- 4 GAT layers ----
    const int HCp[4]  = {252, 152, 100, 60};   // fp32 GEMM-out leading dim
    const int ldoA[4] = {256, 160, 128, 64};   // bf16 act leading dim (= next Kp)
    const int ldaA[4] = {336, 256, 160, 128};  // A leading dim into GEMM
    for (int l = 0; l < 4; ++l) {
        int C = Nc[l] / 2, HC = Nc[l];
        float* alS = alSD + (size_t)l * N * 4;
        float* alD = alS + (size_t)N * 2;
        if (l == 0) {
            gemm_mfma<128><<<dim3(2, N / 128), 256, 0, stream>>>(
                x, 336, nullptr, nullptr, 336, 352,
                WtHi[0], WtLo[0], nullptr, 0,
                bufC, nullptr, nullptr, HCp[0], HCp[0], 0,
                AS[0], AD[0], alS, alD, C, HC);
        } else if (l == 1) {
            gemm_mfma<64><<<dim3(3, N / 128), 256, 0, stream>>>(
                nullptr, 0, actHi, actLo, ldaA[1], KpConv[1],
                WtHi[1], WtLo[1], nullptr, 0,
                bufC, nullptr, nullptr, HCp[1], HCp[1], 0,
                AS[1], AD[1], alS, alD, C, HC);
        } else if (l == 2) {
            gemm_mfma<128><<<dim3(1, N / 128), 256, 0, stream>>>(
                nullptr, 0, actHi, actLo, ldaA[2], KpConv[2],
                WtHi[2], WtLo[2], nullptr, 0,
                bufC, nullptr, nullptr, HCp[2], HCp[2], 0,
                AS[2], AD[2], alS, alD, C, HC);
        } else {
            gemm_mfma<64><<<dim3(1, N / 128), 256, 0, stream>>>(
                nullptr, 0, actHi, actLo, ldaA[3], KpConv[3],
                WtHi[3], WtLo[3], nullptr, 0,
                bufC, nullptr, nullptr, HCp[3], HCp[3], 0,
                AS[3], AD[3], alS, alD, C, HC);
        }
        if (l == 0) {
            attn_meta<<<N / 4, 256, 0, stream>>>(alS, alD, indptr, csr, meta, N);
            gat_gather<32, 2><<<N * 2 / 4, 256, 0, stream>>>(
                bufC, meta, indptr, Bc[0],
                actHi, actLo, ldoA[0], N, C, HC, HCp[0]);
        } else if (l == 1) {
            attn_meta<<<N / 4, 256, 0, stream>>>(alS, alD, indptr, csr, meta, N);
            gat_gather<32, 2><<<N * 2 / 4, 256, 0, stream>>>(
                bufC, meta, indptr, Bc[1],
                actHi, actLo, ldoA[1], N, C, HC, HCp[1]);
        } else if (l == 2) {
            gat_gather_fused<32><<<N / 4, 256, 0, stream>>>(
                bufC, alS, alD, indptr, csr, Bc[2],
                actHi, actLo, ldoA[2], N, C, HC, HCp[2]);
        } else {
            gat_gather_fused<16><<<N / 4, 256, 0, stream>>>(
                bufC, alS, alD, indptr, csr, Bc[3],
                actHi, actLo, ldoA[3], N, C, HC, HCp[3]);
        }
    }

    // ---- MLP head, fused: [8192,480(512 remapped)] -> 200 -> 100 -> 100 -> 29 ----
    mlp_fused<<<8192 / 32, 256, 0, stream>>>(
        actHi, actLo,
        LtHi[0], LtLo[0], LtHi[1], LtLo[1],
        LtHi[2], LtLo[2], LtHi[3], LtLo[3],
        LB[0], LB[1], LB[2], LB[3],
        (float*)d_out);
}